// Round 7
// baseline (3741.890 us; speedup 1.0000x reference)
//
#include <hip/hip_runtime.h>

#define N_NODES 100000
#define N_EDGES 3200000
#define IN_F 500
#define HID 64
#define OUT_F 64
#define ALPHA 0.1f
#define K_ITERS 10
#define SCAN_B ((N_NODES + 255) / 256)   // 391

#define NPART 8                          // XCD count (m09)
#define PART_N (N_NODES / NPART)         // 12500
#define FILL_GRID 2048                   // 8 blocks/CU x 256 CU

#define SPLIT_CHUNK 2560                 // edges per block in split_edges
#define SPLIT_ROUNDS 10                  // 2560 / 256
#define SPLIT_GRID (N_EDGES / SPLIT_CHUNK)   // 1250 exactly

#define KPAD 512                // IN_F padded to MFMA K-step multiple

// ---- spmm chunking: 13 src-chunks of 8192 nodes (1 MB of z each) ----------
#define ZCH_SHIFT 13
#define ZCHUNKS 13                       // 99999>>13 == 12
#define NPW 8                            // nodes per wave (acc in registers)
#define SPMM_GRID (N_NODES / (NPW * 4))  // 3125 blocks x 4 waves x 8 nodes

typedef unsigned short ushort_t;
typedef unsigned int uint_t;
typedef unsigned char uchar_t;
typedef __attribute__((ext_vector_type(8))) short bf16x8;   // MFMA A/B frag
typedef __attribute__((ext_vector_type(4))) float f32x4;    // MFMA C/D frag
typedef int iv2 __attribute__((ext_vector_type(2)));
typedef unsigned int u32x4 __attribute__((ext_vector_type(4)));

__device__ __forceinline__ float bf2f(ushort_t v) {
    union { uint_t u; float f; } c; c.u = ((uint_t)v) << 16; return c.f;
}
__device__ __forceinline__ ushort_t f2b(float f) {
    union { float f; uint_t u; } c; c.f = f;
    uint_t u = c.u + 0x7fffu + ((c.u >> 16) & 1u);   // round-to-nearest-even
    return (ushort_t)(u >> 16);
}
__device__ __forceinline__ float bflo(uint_t u) {
    union { uint_t u; float f; } c; c.u = u << 16; return c.f;
}
__device__ __forceinline__ float bfhi(uint_t u) {
    union { uint_t u; float f; } c; c.u = u & 0xffff0000u; return c.f;
}
__device__ __forceinline__ uint_t packbf(float a, float b) {
    return (uint_t)f2b(a) | ((uint_t)f2b(b) << 16);
}
__device__ __forceinline__ bf16x8 pack8(float4 a, float4 b) {
    bf16x8 r;
    r[0] = (short)f2b(a.x); r[1] = (short)f2b(a.y);
    r[2] = (short)f2b(a.z); r[3] = (short)f2b(a.w);
    r[4] = (short)f2b(b.x); r[5] = (short)f2b(b.y);
    r[6] = (short)f2b(b.z); r[7] = (short)f2b(b.w);
    return r;
}

// ---------------------------------------------------------------------------
// Weight prep: W1 -> w1t bf16 [64][512] (transposed, K zero-padded),
// W2 -> w2t bf16 [64][64] (transposed). One-shot.
// ---------------------------------------------------------------------------
__global__ __launch_bounds__(256) void prep_weights(
    const float* __restrict__ W1, const float* __restrict__ W2,
    ushort_t* __restrict__ w1t, ushort_t* __restrict__ w2t)
{
    int i = blockIdx.x * 256 + threadIdx.x;
    if (i < 64 * KPAD) {
        int c = i >> 9, k = i & (KPAD - 1);
        float v = (k < IN_F) ? W1[k * HID + c] : 0.f;
        w1t[c * KPAD + k] = f2b(v);
    } else {
        int j = i - 64 * KPAD;
        if (j < 64 * 64) {
            int c = j >> 6, k = j & 63;
            w2t[c * 64 + k] = f2b(W2[k * OUT_F + c]);
        }
    }
}

// ---------------------------------------------------------------------------
// MFMA MLP (unchanged from round 5; 134 us measured, conflicts 0).
// ---------------------------------------------------------------------------
__global__ __launch_bounds__(256, 2) void mlp_mfma(
    const float* __restrict__ x, const ushort_t* __restrict__ w1t,
    const float* __restrict__ b1, const ushort_t* __restrict__ w2t,
    const float* __restrict__ b2, ushort_t* __restrict__ hb,
    ushort_t* __restrict__ ahb)
{
    __shared__ ushort_t hs[4][16][64];

    const int lane = threadIdx.x & 63;
    const int wid  = threadIdx.x >> 6;
    const int r16  = lane & 15;
    const int kg   = lane >> 4;
    const int rowbase = blockIdx.x * 64 + wid * 16;

    int arow  = rowbase + r16;
    int lrow  = (arow < N_NODES) ? arow : (N_NODES - 1);
    const float* xr = x + (long)lrow * IN_F;

    f32x4 acc[4];
    #pragma unroll
    for (int t = 0; t < 4; ++t) acc[t] = (f32x4){0.f, 0.f, 0.f, 0.f};

    const float4 z4 = make_float4(0.f, 0.f, 0.f, 0.f);

#define XLD(PA, PB, KS) do {                                      \
        PA = *(const float4*)(xr + (KS) * 32 + kg * 8);           \
        PB = *(const float4*)(xr + (KS) * 32 + kg * 8 + 4);       \
    } while (0)
#define XLDT(PA, PB) do {                                         \
        PA = (kg <= 2) ? *(const float4*)(xr + 480 + kg * 8) : z4;\
        PB = (kg <= 1) ? *(const float4*)(xr + 484 + kg * 8) : z4;\
    } while (0)
#define XMM(PA, PB, KS) do {                                      \
        bf16x8 af_ = pack8(PA, PB);                               \
        _Pragma("unroll")                                         \
        for (int t = 0; t < 4; ++t) {                             \
            bf16x8 bw_ = *(const bf16x8*)&w1t[(t * 16 + r16) * KPAD + (KS) * 32 + kg * 8]; \
            acc[t] = __builtin_amdgcn_mfma_f32_16x16x32_bf16(af_, bw_, acc[t], 0, 0, 0);   \
        }                                                         \
    } while (0)

    float4 a0,b0,a1,b1_,a2,b2_,a3,b3,a4,b4,a5,b5,a6,b6,a7,b7;
    XLD(a0,b0,0);  XLD(a1,b1_,1); XLD(a2,b2_,2); XLD(a3,b3,3);
    XLD(a4,b4,4);  XLD(a5,b5,5);  XLD(a6,b6,6);  XLD(a7,b7,7);
    XMM(a0,b0,0);  XMM(a1,b1_,1); XMM(a2,b2_,2); XMM(a3,b3,3);
    XLD(a0,b0,8);  XLD(a1,b1_,9); XLD(a2,b2_,10); XLD(a3,b3,11);
    XMM(a4,b4,4);  XMM(a5,b5,5);  XMM(a6,b6,6);  XMM(a7,b7,7);
    XLD(a4,b4,12); XLD(a5,b5,13); XLD(a6,b6,14); XLDT(a7,b7);
    XMM(a0,b0,8);  XMM(a1,b1_,9); XMM(a2,b2_,10); XMM(a3,b3,11);
    XMM(a4,b4,12); XMM(a5,b5,13); XMM(a6,b6,14); XMM(a7,b7,15);
#undef XLD
#undef XLDT
#undef XMM

    #pragma unroll
    for (int t = 0; t < 4; ++t) {
        float bb = b1[t * 16 + r16];
        #pragma unroll
        for (int r = 0; r < 4; ++r) {
            float h = fmaxf(acc[t][r] + bb, 0.f);
            int row = kg * 4 + r;
            int col = (t * 16 + r16) ^ ((row & 7) << 3);
            hs[wid][row][col] = f2b(h);
        }
    }
    __syncthreads();

    f32x4 acc2[4];
    #pragma unroll
    for (int t = 0; t < 4; ++t) acc2[t] = (f32x4){0.f, 0.f, 0.f, 0.f};

    #pragma unroll
    for (int ks = 0; ks < 2; ++ks) {
        int colr = (ks * 32 + kg * 8) ^ ((r16 & 7) << 3);
        bf16x8 ha = *(const bf16x8*)&hs[wid][r16][colr];
        #pragma unroll
        for (int t = 0; t < 4; ++t) {
            bf16x8 wb = *(const bf16x8*)&w2t[(t * 16 + r16) * 64 + ks * 32 + kg * 8];
            acc2[t] = __builtin_amdgcn_mfma_f32_16x16x32_bf16(ha, wb, acc2[t], 0, 0, 0);
        }
    }

    #pragma unroll
    for (int t = 0; t < 4; ++t) {
        float bb = b2[t * 16 + r16];
        #pragma unroll
        for (int r = 0; r < 4; ++r) {
            int orow = rowbase + kg * 4 + r;
            if (orow < N_NODES) {
                float v = acc2[t][r] + bb;
                hb[orow * 64 + t * 16 + r16]  = f2b(v);
                ahb[orow * 64 + t * 16 + r16] = f2b(ALPHA * v);
            }
        }
    }
}

// ---------------------------------------------------------------------------
// CSR build: count -> scan -> partition split -> in-slice scatter -> row sort
// ---------------------------------------------------------------------------
__global__ __launch_bounds__(256) void zero_cnt(int* __restrict__ cnt)
{
    int i = blockIdx.x * 256 + threadIdx.x;
    if (i < N_NODES) cnt[i] = 0;
}

__global__ __launch_bounds__(256) void count_keys(
    const int* __restrict__ key, int* __restrict__ cnt)
{
    int i = blockIdx.x * 256 + threadIdx.x;
    if (i < N_EDGES) atomicAdd(&cnt[key[i]], 1);
}

__global__ __launch_bounds__(256) void scan_block_sums(
    const int* __restrict__ cnt, int* __restrict__ bsum)
{
    int i = blockIdx.x * 256 + threadIdx.x;
    int v = (i < N_NODES) ? cnt[i] : 0;
    for (int off = 32; off; off >>= 1) v += __shfl_down(v, off);
    __shared__ int ws_[4];
    if ((threadIdx.x & 63) == 0) ws_[threadIdx.x >> 6] = v;
    __syncthreads();
    if (threadIdx.x == 0) bsum[blockIdx.x] = ws_[0] + ws_[1] + ws_[2] + ws_[3];
}

__global__ __launch_bounds__(512) void scan_partials(
    const int* __restrict__ bsum, int* __restrict__ boff)
{
    int t = threadIdx.x;
    int v = (t < SCAN_B) ? bsum[t] : 0;
    int lane = t & 63, w = t >> 6;
    int x = v;
    for (int off = 1; off < 64; off <<= 1) {
        int y = __shfl_up(x, off);
        if (lane >= off) x += y;
    }
    __shared__ int wsum[8];
    if (lane == 63) wsum[w] = x;
    __syncthreads();
    if (w == 0) {
        int s = (lane < 8) ? wsum[lane] : 0;
        for (int off = 1; off < 8; off <<= 1) {
            int y = __shfl_up(s, off);
            if (lane >= off) s += y;
        }
        if (lane < 8) wsum[lane] = s;
    }
    __syncthreads();
    int wpre = (w == 0) ? 0 : wsum[w - 1];
    if (t < SCAN_B) boff[t] = wpre + x - v;
}

__global__ __launch_bounds__(256) void scan_final(
    const int* __restrict__ cnt, const int* __restrict__ boff,
    int* __restrict__ row_start, int* __restrict__ pos,
    int* __restrict__ pcur)
{
    int i = blockIdx.x * 256 + threadIdx.x;
    int v = (i < N_NODES) ? cnt[i] : 0;
    int lane = threadIdx.x & 63, w = threadIdx.x >> 6;
    int x = v;
    for (int off = 1; off < 64; off <<= 1) {
        int y = __shfl_up(x, off);
        if (lane >= off) x += y;
    }
    __shared__ int wsum[4];
    if (lane == 63) wsum[w] = x;
    __syncthreads();
    int wpre = 0;
    for (int ww = 0; ww < w; ++ww) wpre += wsum[ww];
    int excl = wpre + x - v;
    int r = boff[blockIdx.x] + excl;
    if (i < N_NODES) {
        row_start[i] = r; pos[i] = r;
        if ((i % PART_N) == 0) pcur[i / PART_N] = r;
    }
    if (i == 0) row_start[N_NODES] = N_EDGES;
}

__global__ __launch_bounds__(256) void split_edges(
    const int* __restrict__ esrc, const int* __restrict__ edst,
    const float* __restrict__ ew, int* __restrict__ pcur,
    int2* __restrict__ sbuf)
{
    __shared__ int lbase[NPART];
    const int tid  = threadIdx.x;
    const int lane = tid & 63;
    const int base = blockIdx.x * SPLIT_CHUNK;
    const unsigned long long below = (lane == 63) ? ~0ull >> 1
                                                  : (1ull << lane) - 1ull;

    if (tid < NPART) lbase[tid] = 0;
    __syncthreads();

    int parts[SPLIT_ROUNDS];
    int dloc[SPLIT_ROUNDS];
    int myc = 0;
    #pragma unroll
    for (int k = 0; k < SPLIT_ROUNDS; ++k) {
        int d = edst[base + k * 256 + tid];
        int p = d / PART_N;
        parts[k] = p;
        dloc[k]  = d - p * PART_N;
        #pragma unroll
        for (int pp = 0; pp < NPART; ++pp) {
            unsigned long long m = __ballot(p == pp);
            if (lane == pp) myc += __popcll(m);
        }
    }
    if (lane < NPART) atomicAdd(&lbase[lane], myc);
    __syncthreads();
    if (tid < NPART) lbase[tid] = atomicAdd(&pcur[tid], lbase[tid]);
    __syncthreads();

    #pragma unroll
    for (int k = 0; k < SPLIT_ROUNDS; ++k) {
        const int p = parts[k];
        int slot = 0;
        #pragma unroll
        for (int pp = 0; pp < NPART; ++pp) {
            unsigned long long m = __ballot(p == pp);
            int b = 0;
            if (lane == pp) b = atomicAdd(&lbase[pp], __popcll(m));
            b = __shfl(b, pp, 64);
            if (p == pp) slot = b + __popcll(m & below);
        }
        int i = base + k * 256 + tid;
        int s = esrc[i];
        float w = 0.9f * ew[i];
        sbuf[slot] = make_int2((dloc[k] << 17) | s, __float_as_int(w));
    }
}

__global__ __launch_bounds__(256) void fill_b(
    const int2* __restrict__ sbuf, const int* __restrict__ row_start,
    int* __restrict__ pos, int2* __restrict__ csr)
{
    const int part = blockIdx.x & (NPART - 1);
    const int lo_e = row_start[part * PART_N];
    const int hi_e = row_start[(part + 1) * PART_N];
    const int stride = (FILL_GRID / NPART) * 256;
    for (int i = lo_e + (blockIdx.x >> 3) * 256 + (int)threadIdx.x; i < hi_e;
         i += stride) {
        int2 e = sbuf[i];
        int s = e.x & 0x1ffff;
        int d = part * PART_N + (((unsigned)e.x) >> 17);
        int q = atomicAdd(&pos[d], 1);
        csr[q] = make_int2(s, e.y);
    }
}

// ---------------------------------------------------------------------------
// In-row bitonic sort by src + per-row chunk boundaries for spmm_chunked.
// rcs[node*16+c] (uchar, c=0..13): offset from row start of the first edge
// with src >= c*8192. Fallback for deg>64 (essentially never, but must be
// correct): sentinel 255 for c>=1 => whole row processed in phase 0.
// ---------------------------------------------------------------------------
__global__ __launch_bounds__(256) void sort_rows(
    const int* __restrict__ row_start, int2* __restrict__ csr,
    uchar_t* __restrict__ rcs)
{
    const int node = blockIdx.x * 4 + (threadIdx.x >> 6);
    const int lane = threadIdx.x & 63;
    const int s0 = row_start[node];
    const int s1 = row_start[node + 1];
    const int n_full = s1 - s0;
    int n = n_full; if (n > 64) n = 64;
    int key = 0x7fffffff;
    int val = 0;
    if (lane < n) { int2 e = csr[s0 + lane]; key = e.x; val = e.y; }
    #pragma unroll
    for (int k = 2; k <= 64; k <<= 1) {
        #pragma unroll
        for (int j = k >> 1; j > 0; j >>= 1) {
            int pk = __shfl_xor(key, j, 64);
            int pv = __shfl_xor(val, j, 64);
            bool lower   = (lane & j) == 0;
            bool asc     = (lane & k) == 0;
            bool takeMin = (lower == asc);
            bool pick    = takeMin ? (pk < key) : (pk > key);
            if (pick) { key = pk; val = pv; }
        }
    }
    if (lane < n) csr[s0 + lane] = make_int2(key, val);

    if (n_full > 64) {
        if (lane >= 1 && lane <= 13) rcs[(node << 4) + lane] = 255;
        if (lane == 0) rcs[node << 4] = 0;
    } else {
        if (lane == 0) {
            rcs[node << 4] = 0;
            rcs[(node << 4) + 13] = (uchar_t)n_full;
        }
        for (int c = 1; c <= 12; ++c) {
            unsigned long long m = __ballot(key < (c << ZCH_SHIFT));
            if (lane == 0) rcs[(node << 4) + c] = (uchar_t)__popcll(m);
        }
    }
}

// ---------------------------------------------------------------------------
// Src-chunked register-persistent pull SpMM. Round-5 analysis: old spmm =
// ~88 us/iter, L3-BW-bound on 410 MB of z gathers (z=12.8MB >> 4MB/XCD L2,
// ~70% of gathers fall to L3; 435MB @ ~5TB/s == 88us). Here each wave owns
// NPW=8 dst nodes with acc[8][8] in registers across 13 src-chunk phases
// (chunk = 8192 src nodes = 1 MB of z). All resident waves sweep chunks in
// the same order -> during phase c every XCD L2 holds the same 1 MB z slice
// -> gathers hit L2 (34 TB/s) instead of L3. csr/ahb are nontemporal-loaded
// and z stores nontemporal so streaming doesn't evict the chunk.
// Per round: 8 csr-packs then 8 gathers issued back-to-back (16 VMEM in
// flight). Masked slots read z row 0 (L1-hot, no traffic). Correctness is
// phase-timing independent: every edge processed exactly once.
// ---------------------------------------------------------------------------
#define FMA8N(NN, WV, ZV) do { \
        acc[NN][0] = fmaf((WV), bflo((ZV).x), acc[NN][0]); \
        acc[NN][1] = fmaf((WV), bfhi((ZV).x), acc[NN][1]); \
        acc[NN][2] = fmaf((WV), bflo((ZV).y), acc[NN][2]); \
        acc[NN][3] = fmaf((WV), bfhi((ZV).y), acc[NN][3]); \
        acc[NN][4] = fmaf((WV), bflo((ZV).z), acc[NN][4]); \
        acc[NN][5] = fmaf((WV), bfhi((ZV).z), acc[NN][5]); \
        acc[NN][6] = fmaf((WV), bflo((ZV).w), acc[NN][6]); \
        acc[NN][7] = fmaf((WV), bfhi((ZV).w), acc[NN][7]); \
    } while (0)

template <bool FINAL>
__global__ __launch_bounds__(256, 2) void spmm_chunked(
    const int* __restrict__ row_start, const uchar_t* __restrict__ rcs,
    const int2* __restrict__ csr, const ushort_t* __restrict__ zin,
    const ushort_t* __restrict__ ahb, void* __restrict__ zout)
{
    const int wv = blockIdx.x * 4 + (threadIdx.x >> 6);
    const int n0 = wv * NPW;
    const int lane = threadIdx.x & 63;
    const int g = lane >> 3;     // edge slot 0..7
    const int q = lane & 7;      // feature octet

    int s0[NPW], dg[NPW];
    #pragma unroll
    for (int nn = 0; nn < NPW; ++nn) {
        s0[nn] = __builtin_amdgcn_readfirstlane(row_start[n0 + nn]);
        dg[nn] = __builtin_amdgcn_readfirstlane(row_start[n0 + nn + 1]) - s0[nn];
    }

    float acc[NPW][8];
    #pragma unroll
    for (int nn = 0; nn < NPW; ++nn) {
        u32x4 t = __builtin_nontemporal_load(
            (const u32x4*)&ahb[(n0 + nn) * 64 + 8 * q]);
        bool sd = (g == 0);
        acc[nn][0] = sd ? bflo(t.x) : 0.f; acc[nn][1] = sd ? bfhi(t.x) : 0.f;
        acc[nn][2] = sd ? bflo(t.y) : 0.f; acc[nn][3] = sd ? bfhi(t.y) : 0.f;
        acc[nn][4] = sd ? bflo(t.z) : 0.f; acc[nn][5] = sd ? bfhi(t.z) : 0.f;
        acc[nn][6] = sd ? bflo(t.w) : 0.f; acc[nn][7] = sd ? bfhi(t.w) : 0.f;
    }

    for (int c = 0; c < ZCHUNKS; ++c) {
        int jc[NPW], je[NPW];
        int rmax = 0;
        #pragma unroll
        for (int nn = 0; nn < NPW; ++nn) {
            int b0 = rcs[((n0 + nn) << 4) + c];
            int b1 = rcs[((n0 + nn) << 4) + c + 1];
            b0 = (b0 == 255) ? dg[nn] : b0;
            b1 = (b1 == 255) ? dg[nn] : b1;
            jc[nn] = s0[nn] + b0;
            je[nn] = s0[nn] + b1;
            int len = b1 - b0;
            rmax = (len > rmax) ? len : rmax;
        }
        rmax = __builtin_amdgcn_readfirstlane(rmax);

        for (int r = 0; r < rmax; r += 8) {
            iv2 e[NPW];
            #pragma unroll
            for (int nn = 0; nn < NPW; ++nn) {
                int jj = jc[nn] + r + g;
                e[nn] = (jj < je[nn])
                    ? __builtin_nontemporal_load((const iv2*)csr + jj)
                    : (iv2){0, 0};
            }
            u32x4 zt[NPW];
            #pragma unroll
            for (int nn = 0; nn < NPW; ++nn)
                zt[nn] = *(const u32x4*)&zin[e[nn].x * 64 + 8 * q];
            #pragma unroll
            for (int nn = 0; nn < NPW; ++nn) {
                float wt = __int_as_float(e[nn].y);
                FMA8N(nn, wt, zt[nn]);
            }
        }
    }

    // reduce the 8 edge-slot groups (lane bits 3,4,5) per node, then store
    #pragma unroll
    for (int nn = 0; nn < NPW; ++nn) {
        #pragma unroll
        for (int m = 8; m <= 32; m <<= 1) {
            acc[nn][0] += __shfl_xor(acc[nn][0], m, 64);
            acc[nn][1] += __shfl_xor(acc[nn][1], m, 64);
            acc[nn][2] += __shfl_xor(acc[nn][2], m, 64);
            acc[nn][3] += __shfl_xor(acc[nn][3], m, 64);
            acc[nn][4] += __shfl_xor(acc[nn][4], m, 64);
            acc[nn][5] += __shfl_xor(acc[nn][5], m, 64);
            acc[nn][6] += __shfl_xor(acc[nn][6], m, 64);
            acc[nn][7] += __shfl_xor(acc[nn][7], m, 64);
        }
        if (g == 0) {
            if (FINAL) {
                float* op = (float*)zout + (n0 + nn) * 64 + 8 * q;
                f32x4 lo = {acc[nn][0], acc[nn][1], acc[nn][2], acc[nn][3]};
                f32x4 hi = {acc[nn][4], acc[nn][5], acc[nn][6], acc[nn][7]};
                __builtin_nontemporal_store(lo, (f32x4*)op);
                __builtin_nontemporal_store(hi, (f32x4*)(op + 4));
            } else {
                u32x4 pk;
                pk.x = packbf(acc[nn][0], acc[nn][1]);
                pk.y = packbf(acc[nn][2], acc[nn][3]);
                pk.z = packbf(acc[nn][4], acc[nn][5]);
                pk.w = packbf(acc[nn][6], acc[nn][7]);
                __builtin_nontemporal_store(
                    pk, (u32x4*)&((ushort_t*)zout)[(n0 + nn) * 64 + 8 * q]);
            }
        }
    }
}
#undef FMA8N

// ---------------------------------------------------------------------------
extern "C" void kernel_launch(void* const* d_in, const int* in_sizes, int n_in,
                              void* d_out, int out_size, void* d_ws, size_t ws_size,
                              hipStream_t stream)
{
    const float* x    = (const float*)d_in[0];
    const int*   esrc = (const int*)d_in[1];
    const int*   edst = (const int*)d_in[2];
    const float* ew   = (const float*)d_in[3];
    const float* W1   = (const float*)d_in[4];
    const float* b1   = (const float*)d_in[5];
    const float* W2   = (const float*)d_in[6];
    const float* b2   = (const float*)d_in[7];
    float* out = (float*)d_out;

    // workspace layout (~67 MB). sbuf (25.6 MB) ALIASES ahb+hb: the CSR build
    // (split+fill_b) runs before mlp_mfma writes hb/ahb.
    char* p = (char*)d_ws;
    ushort_t* ahb = (ushort_t*)p;  p += (size_t)N_NODES * 64 * 2;   // 12.8M
    ushort_t* hb  = (ushort_t*)p;  p += (size_t)N_NODES * 64 * 2;   // 12.8M
    ushort_t* zB  = (ushort_t*)p;  p += (size_t)N_NODES * 64 * 2;   // 12.8M
    int2*  csr     = (int2*)p;     p += (size_t)N_EDGES * 8;        // 25.6M
    int* cnt       = (int*)p;      p += (size_t)N_NODES * 4;
    int* pos       = (int*)p;      p += (size_t)N_NODES * 4;
    int* row_start = (int*)p;      p += (size_t)(N_NODES + 1) * 4;
    int* bsum      = (int*)p;      p += (size_t)SCAN_B * 4;
    int* boff      = (int*)p;      p += (size_t)SCAN_B * 4;
    int* pcur      = (int*)p;      p += (size_t)NPART * 4;
    ushort_t* w1t  = (ushort_t*)p; p += (size_t)64 * KPAD * 2;      // 64 KB
    ushort_t* w2t  = (ushort_t*)p; p += (size_t)64 * 64 * 2;        // 8 KB
    uchar_t* rcs   = (uchar_t*)p;  p += (size_t)N_NODES * 16;       // 1.6M
    int2* sbuf = (int2*)ahb;       // alias: 25.6 MB over ahb+hb

    const int EB = (N_EDGES + 255) / 256;

    hipLaunchKernelGGL(prep_weights, dim3((64 * KPAD + 64 * 64 + 255) / 256),
                       dim3(256), 0, stream, W1, W2, w1t, w2t);

    // CSR build first (sbuf aliases ahb/hb, so this precedes mlp)
    hipLaunchKernelGGL(zero_cnt, dim3(SCAN_B), dim3(256), 0, stream, cnt);
    hipLaunchKernelGGL(count_keys, dim3(EB), dim3(256), 0, stream, edst, cnt);
    hipLaunchKernelGGL(scan_block_sums, dim3(SCAN_B), dim3(256), 0, stream, cnt, bsum);
    hipLaunchKernelGGL(scan_partials, dim3(1), dim3(512), 0, stream, bsum, boff);
    hipLaunchKernelGGL(scan_final, dim3(SCAN_B), dim3(256), 0, stream,
                       cnt, boff, row_start, pos, pcur);
    hipLaunchKernelGGL(split_edges, dim3(SPLIT_GRID), dim3(256), 0, stream,
                       esrc, edst, ew, pcur, sbuf);
    hipLaunchKernelGGL(fill_b, dim3(FILL_GRID), dim3(256), 0, stream,
                       sbuf, row_start, pos, csr);
    hipLaunchKernelGGL(sort_rows, dim3(N_NODES / 4), dim3(256), 0, stream,
                       row_start, csr, rcs);

    // MLP after CSR build (frees the sbuf alias)
    hipLaunchKernelGGL(mlp_mfma, dim3((N_NODES + 63) / 64), dim3(256), 0, stream,
                       x, w1t, b1, w2t, b2, hb, ahb);

    // propagation: strict alternation. it even: ->zB, it odd: ->hb.
    // it=0: hb->zB; ... it=8: hb->zB; final (it=9): zB->out(fp32).
    const ushort_t* zi = hb;
    for (int it = 0; it < K_ITERS - 1; ++it) {
        ushort_t* zo = (it % 2 == 0) ? zB : hb;
        hipLaunchKernelGGL((spmm_chunked<false>), dim3(SPMM_GRID), dim3(256), 0, stream,
                           row_start, rcs, csr, zi, ahb, (void*)zo);
        zi = zo;
    }
    hipLaunchKernelGGL((spmm_chunked<true>), dim3(SPMM_GRID), dim3(256), 0, stream,
                       row_start, rcs, csr, zi, ahb, (void*)out);
}

// Round 8
// 1294.089 us; speedup vs baseline: 2.8915x; 2.8915x over previous
//
#include <hip/hip_runtime.h>

#define N_NODES 100000
#define N_EDGES 3200000
#define IN_F 500
#define HID 64
#define OUT_F 64
#define ALPHA 0.1f
#define K_ITERS 10
#define SCAN_B ((N_NODES + 255) / 256)   // 391

#define NPART 8                          // XCD count (m09)
#define PART_N (N_NODES / NPART)         // 12500
#define FILL_GRID 2048                   // 8 blocks/CU x 256 CU

#define SPLIT_CHUNK 2560                 // edges per block in split_edges
#define SPLIT_ROUNDS 10                  // 2560 / 256
#define SPLIT_GRID (N_EDGES / SPLIT_CHUNK)   // 1250 exactly

#define KPAD 512                // IN_F padded to MFMA K-step multiple

typedef unsigned short ushort_t;
typedef unsigned int uint_t;
typedef __attribute__((ext_vector_type(8))) short bf16x8;   // MFMA A/B frag
typedef __attribute__((ext_vector_type(4))) float f32x4;    // MFMA C/D frag

__device__ __forceinline__ float bf2f(ushort_t v) {
    union { uint_t u; float f; } c; c.u = ((uint_t)v) << 16; return c.f;
}
__device__ __forceinline__ ushort_t f2b(float f) {
    union { float f; uint_t u; } c; c.f = f;
    uint_t u = c.u + 0x7fffu + ((c.u >> 16) & 1u);   // round-to-nearest-even
    return (ushort_t)(u >> 16);
}
__device__ __forceinline__ float bflo(uint_t u) {
    union { uint_t u; float f; } c; c.u = u << 16; return c.f;
}
__device__ __forceinline__ float bfhi(uint_t u) {
    union { uint_t u; float f; } c; c.u = u & 0xffff0000u; return c.f;
}
__device__ __forceinline__ uint_t packbf(float a, float b) {
    return (uint_t)f2b(a) | ((uint_t)f2b(b) << 16);
}
__device__ __forceinline__ bf16x8 pack8(float4 a, float4 b) {
    bf16x8 r;
    r[0] = (short)f2b(a.x); r[1] = (short)f2b(a.y);
    r[2] = (short)f2b(a.z); r[3] = (short)f2b(a.w);
    r[4] = (short)f2b(b.x); r[5] = (short)f2b(b.y);
    r[6] = (short)f2b(b.z); r[7] = (short)f2b(b.w);
    return r;
}

// ---------------------------------------------------------------------------
// Weight prep: W1 -> w1t bf16 [64][512] (transposed, K zero-padded),
// W2 -> w2t bf16 [64][64] (transposed). One-shot.
// ---------------------------------------------------------------------------
__global__ __launch_bounds__(256) void prep_weights(
    const float* __restrict__ W1, const float* __restrict__ W2,
    ushort_t* __restrict__ w1t, ushort_t* __restrict__ w2t)
{
    int i = blockIdx.x * 256 + threadIdx.x;
    if (i < 64 * KPAD) {
        int c = i >> 9, k = i & (KPAD - 1);
        float v = (k < IN_F) ? W1[k * HID + c] : 0.f;
        w1t[c * KPAD + k] = f2b(v);
    } else {
        int j = i - 64 * KPAD;
        if (j < 64 * 64) {
            int c = j >> 6, k = j & 63;
            w2t[c * 64 + k] = f2b(W2[k * OUT_F + c]);
        }
    }
}

// ---------------------------------------------------------------------------
// MFMA MLP, round-8: LDS double-buffered x staging (T14 reg-staged split).
// Round-5 post-mortem: compiler capped VGPR at 64 and re-serialized the
// register pipeline -> latency-bound at 1.07 TB/s (134 us; floor ~36).
// Now: per 64-row x 32-float tile (8 KB), issue next tile's global loads
// into 2 float4 regs (only +8 VGPR) -> compute current tile from LDS
// (ds_read_b128, XOR-swizzle slot^(row&7): 2-way = free) -> barrier ->
// ds_write staged regs -> barrier. Load latency hides under 4 MFMAs;
// low VGPR keeps ~6 blocks/CU (LDS 24 KB) for wave-level overlap.
// Tail k=480..512 stays on the proven register path (w1t zero-padded).
// ---------------------------------------------------------------------------
__global__ __launch_bounds__(256, 2) void mlp_mfma(
    const float* __restrict__ x, const ushort_t* __restrict__ w1t,
    const float* __restrict__ b1, const ushort_t* __restrict__ w2t,
    const float* __restrict__ b2, ushort_t* __restrict__ hb,
    ushort_t* __restrict__ ahb)
{
    __shared__ float xs[2][64][32];      // 2 x 8 KB staging tiles
    __shared__ ushort_t hs[4][16][64];   // layer-2 re-fragment tile, 8 KB

    const int tid  = threadIdx.x;
    const int lane = tid & 63;
    const int wid  = tid >> 6;
    const int r16  = lane & 15;
    const int kg   = lane >> 4;
    const int block_row = blockIdx.x * 64;
    const int rowbase   = block_row + wid * 16;

    // staging geometry: thread covers 16B slots s=tid (rows 0..31) and
    // s=tid+256 (rows 32..63); slot (row,c) stores global col16 c (linear
    // coalesced read), written to LDS slot c^(row&7) (bank swizzle).
    const int s_row0 = tid >> 3;               // 0..31
    const int s_row1 = s_row0 + 32;            // 32..63
    const int s_c    = tid & 7;
    int grow0 = block_row + s_row0; if (grow0 > N_NODES - 1) grow0 = N_NODES - 1;
    int grow1 = block_row + s_row1; if (grow1 > N_NODES - 1) grow1 = N_NODES - 1;
    const float* gx0 = x + (size_t)grow0 * IN_F + s_c * 4;
    const float* gx1 = x + (size_t)grow1 * IN_F + s_c * 4;
    char* xsb = (char*)&xs[0][0][0];
    const int ld0 = s_row0 * 128 + ((s_c ^ (s_row0 & 7)) * 16);
    const int ld1 = s_row1 * 128 + ((s_c ^ (s_row1 & 7)) * 16);

    f32x4 acc[4];
    #pragma unroll
    for (int t = 0; t < 4; ++t) acc[t] = (f32x4){0.f, 0.f, 0.f, 0.f};

    // read-side addressing (byte offsets within a buffer)
    const int lrow  = wid * 16 + r16;
    const int swz   = lrow & 7;
    const int rbase = lrow * 128;
    const int off_a = rbase + (((kg * 2)     ^ swz) * 16);
    const int off_b = rbase + (((kg * 2 + 1) ^ swz) * 16);

#define XMM(PA, PB, KS) do {                                      \
        bf16x8 af_ = pack8(PA, PB);                               \
        _Pragma("unroll")                                         \
        for (int t = 0; t < 4; ++t) {                             \
            bf16x8 bw_ = *(const bf16x8*)&w1t[(t * 16 + r16) * KPAD + (KS) * 32 + kg * 8]; \
            acc[t] = __builtin_amdgcn_mfma_f32_16x16x32_bf16(af_, bw_, acc[t], 0, 0, 0);   \
        }                                                         \
    } while (0)

    // prologue: stage tile 0
    float4 va = *(const float4*)(gx0);
    float4 vb = *(const float4*)(gx1);
    *(float4*)(xsb + ld0) = va;
    *(float4*)(xsb + ld1) = vb;
    __syncthreads();

    int cur = 0;
    for (int ks = 0; ks < 15; ++ks) {
        if (ks < 14) {                       // issue next tile's global loads
            va = *(const float4*)(gx0 + (ks + 1) * 32);
            vb = *(const float4*)(gx1 + (ks + 1) * 32);
        }
        const char* bb = xsb + cur * 8192;
        float4 fa = *(const float4*)(bb + off_a);
        float4 fb = *(const float4*)(bb + off_b);
        XMM(fa, fb, ks);
        __syncthreads();                     // all reads of buf[cur] done
        if (ks < 14) {                       // write tile ks+1 into buf[cur^1]
            char* wb = xsb + (cur ^ 1) * 8192;
            *(float4*)(wb + ld0) = va;
            *(float4*)(wb + ld1) = vb;
        }
        __syncthreads();                     // writes visible for next iter
        cur ^= 1;
    }

    // tail: k in [480,512), zero-fill beyond 500 (w1t zero-padded there)
    {
        const float4 z4 = make_float4(0.f, 0.f, 0.f, 0.f);
        int arow = rowbase + r16;
        int lrow2 = (arow < N_NODES) ? arow : (N_NODES - 1);
        const float* xr = x + (size_t)lrow2 * IN_F;
        float4 ta = (kg <= 2) ? *(const float4*)(xr + 480 + kg * 8) : z4;
        float4 tb = (kg <= 1) ? *(const float4*)(xr + 484 + kg * 8) : z4;
        XMM(ta, tb, 15);
    }
#undef XMM

    // bias + relu, stash hidden tile. C/D layout: row=kg*4+r, col=t*16+r16.
    #pragma unroll
    for (int t = 0; t < 4; ++t) {
        float bb = b1[t * 16 + r16];
        #pragma unroll
        for (int r = 0; r < 4; ++r) {
            float h = fmaxf(acc[t][r] + bb, 0.f);
            int row = kg * 4 + r;
            int col = (t * 16 + r16) ^ ((row & 7) << 3);
            hs[wid][row][col] = f2b(h);
        }
    }
    __syncthreads();

    f32x4 acc2[4];
    #pragma unroll
    for (int t = 0; t < 4; ++t) acc2[t] = (f32x4){0.f, 0.f, 0.f, 0.f};

    #pragma unroll
    for (int ks = 0; ks < 2; ++ks) {
        int colr = (ks * 32 + kg * 8) ^ ((r16 & 7) << 3);
        bf16x8 ha = *(const bf16x8*)&hs[wid][r16][colr];
        #pragma unroll
        for (int t = 0; t < 4; ++t) {
            bf16x8 wb = *(const bf16x8*)&w2t[(t * 16 + r16) * 64 + ks * 32 + kg * 8];
            acc2[t] = __builtin_amdgcn_mfma_f32_16x16x32_bf16(ha, wb, acc2[t], 0, 0, 0);
        }
    }

    #pragma unroll
    for (int t = 0; t < 4; ++t) {
        float bb = b2[t * 16 + r16];
        #pragma unroll
        for (int r = 0; r < 4; ++r) {
            int orow = rowbase + kg * 4 + r;
            if (orow < N_NODES) {
                float v = acc2[t][r] + bb;
                hb[orow * 64 + t * 16 + r16]  = f2b(v);
                ahb[orow * 64 + t * 16 + r16] = f2b(ALPHA * v);
            }
        }
    }
}

// ---------------------------------------------------------------------------
// CSR build: count -> scan -> partition split -> in-slice scatter -> row sort
// ---------------------------------------------------------------------------
__global__ __launch_bounds__(256) void zero_cnt(int* __restrict__ cnt)
{
    int i = blockIdx.x * 256 + threadIdx.x;
    if (i < N_NODES) cnt[i] = 0;
}

__global__ __launch_bounds__(256) void count_keys(
    const int* __restrict__ key, int* __restrict__ cnt)
{
    int i = blockIdx.x * 256 + threadIdx.x;
    if (i < N_EDGES) atomicAdd(&cnt[key[i]], 1);
}

__global__ __launch_bounds__(256) void scan_block_sums(
    const int* __restrict__ cnt, int* __restrict__ bsum)
{
    int i = blockIdx.x * 256 + threadIdx.x;
    int v = (i < N_NODES) ? cnt[i] : 0;
    for (int off = 32; off; off >>= 1) v += __shfl_down(v, off);
    __shared__ int ws_[4];
    if ((threadIdx.x & 63) == 0) ws_[threadIdx.x >> 6] = v;
    __syncthreads();
    if (threadIdx.x == 0) bsum[blockIdx.x] = ws_[0] + ws_[1] + ws_[2] + ws_[3];
}

__global__ __launch_bounds__(512) void scan_partials(
    const int* __restrict__ bsum, int* __restrict__ boff)
{
    int t = threadIdx.x;
    int v = (t < SCAN_B) ? bsum[t] : 0;
    int lane = t & 63, w = t >> 6;
    int x = v;
    for (int off = 1; off < 64; off <<= 1) {
        int y = __shfl_up(x, off);
        if (lane >= off) x += y;
    }
    __shared__ int wsum[8];
    if (lane == 63) wsum[w] = x;
    __syncthreads();
    if (w == 0) {
        int s = (lane < 8) ? wsum[lane] : 0;
        for (int off = 1; off < 8; off <<= 1) {
            int y = __shfl_up(s, off);
            if (lane >= off) s += y;
        }
        if (lane < 8) wsum[lane] = s;
    }
    __syncthreads();
    int wpre = (w == 0) ? 0 : wsum[w - 1];
    if (t < SCAN_B) boff[t] = wpre + x - v;
}

__global__ __launch_bounds__(256) void scan_final(
    const int* __restrict__ cnt, const int* __restrict__ boff,
    int* __restrict__ row_start, int* __restrict__ pos,
    int* __restrict__ pcur)
{
    int i = blockIdx.x * 256 + threadIdx.x;
    int v = (i < N_NODES) ? cnt[i] : 0;
    int lane = threadIdx.x & 63, w = threadIdx.x >> 6;
    int x = v;
    for (int off = 1; off < 64; off <<= 1) {
        int y = __shfl_up(x, off);
        if (lane >= off) x += y;
    }
    __shared__ int wsum[4];
    if (lane == 63) wsum[w] = x;
    __syncthreads();
    int wpre = 0;
    for (int ww = 0; ww < w; ++ww) wpre += wsum[ww];
    int excl = wpre + x - v;
    int r = boff[blockIdx.x] + excl;
    if (i < N_NODES) {
        row_start[i] = r; pos[i] = r;
        if ((i % PART_N) == 0) pcur[i / PART_N] = r;
    }
    if (i == 0) row_start[N_NODES] = N_EDGES;
}

__global__ __launch_bounds__(256) void split_edges(
    const int* __restrict__ esrc, const int* __restrict__ edst,
    const float* __restrict__ ew, int* __restrict__ pcur,
    int2* __restrict__ sbuf)
{
    __shared__ int lbase[NPART];
    const int tid  = threadIdx.x;
    const int lane = tid & 63;
    const int base = blockIdx.x * SPLIT_CHUNK;
    const unsigned long long below = (lane == 63) ? ~0ull >> 1
                                                  : (1ull << lane) - 1ull;

    if (tid < NPART) lbase[tid] = 0;
    __syncthreads();

    int parts[SPLIT_ROUNDS];
    int dloc[SPLIT_ROUNDS];
    int myc = 0;
    #pragma unroll
    for (int k = 0; k < SPLIT_ROUNDS; ++k) {
        int d = edst[base + k * 256 + tid];
        int p = d / PART_N;
        parts[k] = p;
        dloc[k]  = d - p * PART_N;
        #pragma unroll
        for (int pp = 0; pp < NPART; ++pp) {
            unsigned long long m = __ballot(p == pp);
            if (lane == pp) myc += __popcll(m);
        }
    }
    if (lane < NPART) atomicAdd(&lbase[lane], myc);
    __syncthreads();
    if (tid < NPART) lbase[tid] = atomicAdd(&pcur[tid], lbase[tid]);
    __syncthreads();

    #pragma unroll
    for (int k = 0; k < SPLIT_ROUNDS; ++k) {
        const int p = parts[k];
        int slot = 0;
        #pragma unroll
        for (int pp = 0; pp < NPART; ++pp) {
            unsigned long long m = __ballot(p == pp);
            int b = 0;
            if (lane == pp) b = atomicAdd(&lbase[pp], __popcll(m));
            b = __shfl(b, pp, 64);
            if (p == pp) slot = b + __popcll(m & below);
        }
        int i = base + k * 256 + tid;
        int s = esrc[i];
        float w = 0.9f * ew[i];
        sbuf[slot] = make_int2((dloc[k] << 17) | s, __float_as_int(w));
    }
}

__global__ __launch_bounds__(256) void fill_b(
    const int2* __restrict__ sbuf, const int* __restrict__ row_start,
    int* __restrict__ pos, int2* __restrict__ csr)
{
    const int part = blockIdx.x & (NPART - 1);
    const int lo_e = row_start[part * PART_N];
    const int hi_e = row_start[(part + 1) * PART_N];
    const int stride = (FILL_GRID / NPART) * 256;
    for (int i = lo_e + (blockIdx.x >> 3) * 256 + (int)threadIdx.x; i < hi_e;
         i += stride) {
        int2 e = sbuf[i];
        int s = e.x & 0x1ffff;
        int d = part * PART_N + (((unsigned)e.x) >> 17);
        int q = atomicAdd(&pos[d], 1);
        csr[q] = make_int2(s, e.y);
    }
}

// In-row bitonic sort by src (locality only — correctness never depends on
// order). One wave per row; sorts first min(len,64) entries.
__global__ __launch_bounds__(256) void sort_rows(
    const int* __restrict__ row_start, int2* __restrict__ csr)
{
    const int node = blockIdx.x * 4 + (threadIdx.x >> 6);
    const int lane = threadIdx.x & 63;
    const int s0 = row_start[node];
    const int s1 = row_start[node + 1];
    int n = s1 - s0; if (n > 64) n = 64;
    int key = 0x7fffffff;
    int val = 0;
    if (lane < n) { int2 e = csr[s0 + lane]; key = e.x; val = e.y; }
    #pragma unroll
    for (int k = 2; k <= 64; k <<= 1) {
        #pragma unroll
        for (int j = k >> 1; j > 0; j >>= 1) {
            int pk = __shfl_xor(key, j, 64);
            int pv = __shfl_xor(val, j, 64);
            bool lower   = (lane & j) == 0;
            bool asc     = (lane & k) == 0;
            bool takeMin = (lower == asc);
            bool pick    = takeMin ? (pk < key) : (pk > key);
            if (pick) { key = pk; val = pv; }
        }
    }
    if (lane < n) csr[s0 + lane] = make_int2(key, val);
}

// ---------------------------------------------------------------------------
// Pull-based SpMM, bf16 z (round-5 version, ~104 us/iter known-good).
// One wave per dst node. 8 lanes x 16 B cover one z-row (64 bf16): one
// global_load_dwordx4 gathers 8 edges -> 8 distinct 128 B lines per VMEM
// instr. Unroll 4 => 32 edge-lines in flight per wave. Row-end reduction:
// 3 shfl_xor rounds over groups.
// ---------------------------------------------------------------------------
template <bool FINAL>
__global__ __launch_bounds__(256) void spmm_kernel(
    const int* __restrict__ row_start, const int2* __restrict__ csr,
    const ushort_t* __restrict__ zin, const ushort_t* __restrict__ ahb,
    void* __restrict__ zout)
{
    const int node = blockIdx.x * 4 + (threadIdx.x >> 6);  // 25000*4 == 100000
    const int lane = threadIdx.x & 63;
    const int g = lane >> 3;    // edge slot 0..7
    const int q = lane & 7;     // feature octet
    const int s0 = __builtin_amdgcn_readfirstlane(row_start[node]);
    const int s1 = __builtin_amdgcn_readfirstlane(row_start[node + 1]);

    float a0=0.f,a1=0.f,a2=0.f,a3=0.f,a4=0.f,a5=0.f,a6=0.f,a7=0.f;
    if (g == 0) {
        uint4 t = *(const uint4*)&ahb[node * 64 + 8 * q];
        a0 = bflo(t.x); a1 = bfhi(t.x); a2 = bflo(t.y); a3 = bfhi(t.y);
        a4 = bflo(t.z); a5 = bfhi(t.z); a6 = bflo(t.w); a7 = bfhi(t.w);
    }

#define FMA8(WV, ZV) do { \
        a0 = fmaf((WV), bflo((ZV).x), a0); a1 = fmaf((WV), bfhi((ZV).x), a1); \
        a2 = fmaf((WV), bflo((ZV).y), a2); a3 = fmaf((WV), bfhi((ZV).y), a3); \
        a4 = fmaf((WV), bflo((ZV).z), a4); a5 = fmaf((WV), bfhi((ZV).z), a5); \
        a6 = fmaf((WV), bflo((ZV).w), a6); a7 = fmaf((WV), bfhi((ZV).w), a7); \
    } while (0)

    int j = s0;
    for (; j + 32 <= s1; j += 32) {
        int2 e0 = csr[j + g];
        int2 e1 = csr[j + 8 + g];
        int2 e2 = csr[j + 16 + g];
        int2 e3 = csr[j + 24 + g];
        uint4 z0 = *(const uint4*)&zin[e0.x * 64 + 8 * q];
        uint4 z1 = *(const uint4*)&zin[e1.x * 64 + 8 * q];
        uint4 z2 = *(const uint4*)&zin[e2.x * 64 + 8 * q];
        uint4 z3 = *(const uint4*)&zin[e3.x * 64 + 8 * q];
        float w0 = __int_as_float(e0.y);
        float w1 = __int_as_float(e1.y);
        float w2 = __int_as_float(e2.y);
        float w3 = __int_as_float(e3.y);
        FMA8(w0, z0);
        FMA8(w1, z1);
        FMA8(w2, z2);
        FMA8(w3, z3);
    }
    for (; j < s1; j += 8) {
        int2 e = make_int2(0, 0);
        int jj = j + g;
        if (jj < s1) e = csr[jj];
        uint4 zt = *(const uint4*)&zin[e.x * 64 + 8 * q];
        float wt = __int_as_float(e.y);
        FMA8(wt, zt);
    }
#undef FMA8

    // reduce the 8 edge-slot groups (lane bits 3,4,5)
    #pragma unroll
    for (int m = 8; m <= 32; m <<= 1) {
        a0 += __shfl_xor(a0, m, 64); a1 += __shfl_xor(a1, m, 64);
        a2 += __shfl_xor(a2, m, 64); a3 += __shfl_xor(a3, m, 64);
        a4 += __shfl_xor(a4, m, 64); a5 += __shfl_xor(a5, m, 64);
        a6 += __shfl_xor(a6, m, 64); a7 += __shfl_xor(a7, m, 64);
    }

    if (g == 0) {
        if (FINAL) {
            float* op = (float*)zout + node * 64 + 8 * q;
            *(float4*)op       = make_float4(a0, a1, a2, a3);
            *(float4*)(op + 4) = make_float4(a4, a5, a6, a7);
        } else {
            uint4 pk;
            pk.x = packbf(a0, a1); pk.y = packbf(a2, a3);
            pk.z = packbf(a4, a5); pk.w = packbf(a6, a7);
            *(uint4*)&((ushort_t*)zout)[node * 64 + 8 * q] = pk;
        }
    }
}

// ---------------------------------------------------------------------------
extern "C" void kernel_launch(void* const* d_in, const int* in_sizes, int n_in,
                              void* d_out, int out_size, void* d_ws, size_t ws_size,
                              hipStream_t stream)
{
    const float* x    = (const float*)d_in[0];
    const int*   esrc = (const int*)d_in[1];
    const int*   edst = (const int*)d_in[2];
    const float* ew   = (const float*)d_in[3];
    const float* W1   = (const float*)d_in[4];
    const float* b1   = (const float*)d_in[5];
    const float* W2   = (const float*)d_in[6];
    const float* b2   = (const float*)d_in[7];
    float* out = (float*)d_out;

    // workspace layout (~65 MB). sbuf (25.6 MB) ALIASES ahb+hb: the CSR build
    // (split+fill_b) runs before mlp_mfma writes hb/ahb.
    char* p = (char*)d_ws;
    ushort_t* ahb = (ushort_t*)p;  p += (size_t)N_NODES * 64 * 2;   // 12.8M
    ushort_t* hb  = (ushort_t*)p;  p += (size_t)N_NODES * 64 * 2;   // 12.8M
    ushort_t* zB  = (ushort_t*)p;  p += (size_t)N_NODES * 64 * 2;   // 12.8M
    int2*  csr     = (int2*)p;     p += (size_t)N_EDGES * 8;        // 25.6M
    int* cnt       = (int*)p;      p += (size_t)N_NODES * 4;
    int* pos       = (int*)p;      p += (size_t)N_NODES * 4;
    int* row_start = (int*)p;      p += (size_t)(N_NODES + 1) * 4;
    int* bsum      = (int*)p;      p += (size_t)SCAN_B * 4;
    int* boff      = (int*)p;      p += (size_t)SCAN_B * 4;
    int* pcur      = (int*)p;      p += (size_t)NPART * 4;
    ushort_t* w1t  = (ushort_t*)p; p += (size_t)64 * KPAD * 2;      // 64 KB
    ushort_t* w2t  = (ushort_t*)p; p += (size_t)64 * 64 * 2;        // 8 KB
    int2* sbuf = (int2*)ahb;       // alias: 25.6 MB over ahb+hb

    const int EB = (N_EDGES + 255) / 256;

    hipLaunchKernelGGL(prep_weights, dim3((64 * KPAD + 64 * 64 + 255) / 256),
                       dim3(256), 0, stream, W1, W2, w1t, w2t);

    // CSR build first (sbuf aliases ahb/hb, so this precedes mlp)
    hipLaunchKernelGGL(zero_cnt, dim3(SCAN_B), dim3(256), 0, stream, cnt);
    hipLaunchKernelGGL(count_keys, dim3(EB), dim3(256), 0, stream, edst, cnt);
    hipLaunchKernelGGL(scan_block_sums, dim3(SCAN_B), dim3(256), 0, stream, cnt, bsum);
    hipLaunchKernelGGL(scan_partials, dim3(1), dim3(512), 0, stream, bsum, boff);
    hipLaunchKernelGGL(scan_final, dim3(SCAN_B), dim3(256), 0, stream,
                       cnt, boff, row_start, pos, pcur);
    hipLaunchKernelGGL(split_edges, dim3(SPLIT_GRID), dim3(256), 0, stream,
                       esrc, edst, ew, pcur, sbuf);
    hipLaunchKernelGGL(fill_b, dim3(FILL_GRID), dim3(256), 0, stream,
                       sbuf, row_start, pos, csr);
    hipLaunchKernelGGL(sort_rows, dim3(N_NODES / 4), dim3(256), 0, stream,
                       row_start, csr);

    // MLP after CSR build (frees the sbuf alias)
    hipLaunchKernelGGL(mlp_mfma, dim3((N_NODES + 63) / 64), dim3(256), 0, stream,
                       x, w1t, b1, w2t, b2, hb, ahb);

    // propagation: strict alternation. it even: ->zB, it odd: ->hb.
    // it=0: hb->zB; ... it=8: hb->zB; final (it=9): zB->out(fp32).
    const ushort_t* zi = hb;
    for (int it = 0; it < K_ITERS - 1; ++it) {
        ushort_t* zo = (it % 2 == 0) ? zB : hb;
        hipLaunchKernelGGL((spmm_kernel<false>), dim3(N_NODES / 4), dim3(256), 0, stream,
                           row_start, csr, zi, ahb, (void*)zo);
        zi = zo;
    }
    hipLaunchKernelGGL((spmm_kernel<true>), dim3(N_NODES / 4), dim3(256), 0, stream,
                       row_start, csr, zi, ahb, (void*)out);
}

// Round 9
// 1273.693 us; speedup vs baseline: 2.9378x; 1.0160x over previous
//
#include <hip/hip_runtime.h>

#define N_NODES 100000
#define N_EDGES 3200000
#define IN_F 500
#define HID 64
#define OUT_F 64
#define ALPHA 0.1f
#define K_ITERS 10
#define SCAN_B ((N_NODES + 255) / 256)   // 391

#define NPART 8                          // XCD count (m09)
#define PART_N (N_NODES / NPART)         // 12500
#define SUB_N 1563                       // 8 sub-buckets per partition (7*1563=10941<12500)
#define NBUCK 64                         // total dst buckets
#define FILL_GRID 2048                   // 64 buckets x 32 blocks

#define SPLIT_CHUNK 2560                 // edges per block in split_edges
#define SPLIT_ROUNDS 10                  // 2560 / 256
#define SPLIT_GRID (N_EDGES / SPLIT_CHUNK)   // 1250 exactly

#define KPAD 512                // IN_F padded to MFMA K-step multiple

typedef unsigned short ushort_t;
typedef unsigned int uint_t;
typedef __attribute__((ext_vector_type(8))) short bf16x8;   // MFMA A/B frag
typedef __attribute__((ext_vector_type(4))) float f32x4;    // MFMA C/D frag
typedef int iv2 __attribute__((ext_vector_type(2)));        // NT-loadable int2

__device__ __forceinline__ float bf2f(ushort_t v) {
    union { uint_t u; float f; } c; c.u = ((uint_t)v) << 16; return c.f;
}
__device__ __forceinline__ ushort_t f2b(float f) {
    union { float f; uint_t u; } c; c.f = f;
    uint_t u = c.u + 0x7fffu + ((c.u >> 16) & 1u);   // round-to-nearest-even
    return (ushort_t)(u >> 16);
}
__device__ __forceinline__ float bflo(uint_t u) {
    union { uint_t u; float f; } c; c.u = u << 16; return c.f;
}
__device__ __forceinline__ float bfhi(uint_t u) {
    union { uint_t u; float f; } c; c.u = u & 0xffff0000u; return c.f;
}
__device__ __forceinline__ uint_t packbf(float a, float b) {
    return (uint_t)f2b(a) | ((uint_t)f2b(b) << 16);
}
__device__ __forceinline__ bf16x8 pack8(float4 a, float4 b) {
    bf16x8 r;
    r[0] = (short)f2b(a.x); r[1] = (short)f2b(a.y);
    r[2] = (short)f2b(a.z); r[3] = (short)f2b(a.w);
    r[4] = (short)f2b(b.x); r[5] = (short)f2b(b.y);
    r[6] = (short)f2b(b.z); r[7] = (short)f2b(b.w);
    return r;
}

// ---------------------------------------------------------------------------
// Weight prep: W1 -> w1t bf16 [64][512] (transposed, K zero-padded),
// W2 -> w2t bf16 [64][64] (transposed). One-shot.
// ---------------------------------------------------------------------------
__global__ __launch_bounds__(256) void prep_weights(
    const float* __restrict__ W1, const float* __restrict__ W2,
    ushort_t* __restrict__ w1t, ushort_t* __restrict__ w2t)
{
    int i = blockIdx.x * 256 + threadIdx.x;
    if (i < 64 * KPAD) {
        int c = i >> 9, k = i & (KPAD - 1);
        float v = (k < IN_F) ? W1[k * HID + c] : 0.f;
        w1t[c * KPAD + k] = f2b(v);
    } else {
        int j = i - 64 * KPAD;
        if (j < 64 * 64) {
            int c = j >> 6, k = j & 63;
            w2t[c * 64 + k] = f2b(W2[k * OUT_F + c]);
        }
    }
}

// ---------------------------------------------------------------------------
// MFMA MLP (round-8 version: LDS double-buffered x staging; left top-5).
// ---------------------------------------------------------------------------
__global__ __launch_bounds__(256, 2) void mlp_mfma(
    const float* __restrict__ x, const ushort_t* __restrict__ w1t,
    const float* __restrict__ b1, const ushort_t* __restrict__ w2t,
    const float* __restrict__ b2, ushort_t* __restrict__ hb,
    ushort_t* __restrict__ ahb)
{
    __shared__ float xs[2][64][32];      // 2 x 8 KB staging tiles
    __shared__ ushort_t hs[4][16][64];   // layer-2 re-fragment tile, 8 KB

    const int tid  = threadIdx.x;
    const int lane = tid & 63;
    const int wid  = tid >> 6;
    const int r16  = lane & 15;
    const int kg   = lane >> 4;
    const int block_row = blockIdx.x * 64;
    const int rowbase   = block_row + wid * 16;

    const int s_row0 = tid >> 3;               // 0..31
    const int s_row1 = s_row0 + 32;            // 32..63
    const int s_c    = tid & 7;
    int grow0 = block_row + s_row0; if (grow0 > N_NODES - 1) grow0 = N_NODES - 1;
    int grow1 = block_row + s_row1; if (grow1 > N_NODES - 1) grow1 = N_NODES - 1;
    const float* gx0 = x + (size_t)grow0 * IN_F + s_c * 4;
    const float* gx1 = x + (size_t)grow1 * IN_F + s_c * 4;
    char* xsb = (char*)&xs[0][0][0];
    const int ld0 = s_row0 * 128 + ((s_c ^ (s_row0 & 7)) * 16);
    const int ld1 = s_row1 * 128 + ((s_c ^ (s_row1 & 7)) * 16);

    f32x4 acc[4];
    #pragma unroll
    for (int t = 0; t < 4; ++t) acc[t] = (f32x4){0.f, 0.f, 0.f, 0.f};

    const int lrow  = wid * 16 + r16;
    const int swz   = lrow & 7;
    const int rbase = lrow * 128;
    const int off_a = rbase + (((kg * 2)     ^ swz) * 16);
    const int off_b = rbase + (((kg * 2 + 1) ^ swz) * 16);

#define XMM(PA, PB, KS) do {                                      \
        bf16x8 af_ = pack8(PA, PB);                               \
        _Pragma("unroll")                                         \
        for (int t = 0; t < 4; ++t) {                             \
            bf16x8 bw_ = *(const bf16x8*)&w1t[(t * 16 + r16) * KPAD + (KS) * 32 + kg * 8]; \
            acc[t] = __builtin_amdgcn_mfma_f32_16x16x32_bf16(af_, bw_, acc[t], 0, 0, 0);   \
        }                                                         \
    } while (0)

    float4 va = *(const float4*)(gx0);
    float4 vb = *(const float4*)(gx1);
    *(float4*)(xsb + ld0) = va;
    *(float4*)(xsb + ld1) = vb;
    __syncthreads();

    int cur = 0;
    for (int ks = 0; ks < 15; ++ks) {
        if (ks < 14) {
            va = *(const float4*)(gx0 + (ks + 1) * 32);
            vb = *(const float4*)(gx1 + (ks + 1) * 32);
        }
        const char* bb = xsb + cur * 8192;
        float4 fa = *(const float4*)(bb + off_a);
        float4 fb = *(const float4*)(bb + off_b);
        XMM(fa, fb, ks);
        __syncthreads();
        if (ks < 14) {
            char* wb = xsb + (cur ^ 1) * 8192;
            *(float4*)(wb + ld0) = va;
            *(float4*)(wb + ld1) = vb;
        }
        __syncthreads();
        cur ^= 1;
    }

    {
        const float4 z4 = make_float4(0.f, 0.f, 0.f, 0.f);
        int arow = rowbase + r16;
        int lrow2 = (arow < N_NODES) ? arow : (N_NODES - 1);
        const float* xr = x + (size_t)lrow2 * IN_F;
        float4 ta = (kg <= 2) ? *(const float4*)(xr + 480 + kg * 8) : z4;
        float4 tb = (kg <= 1) ? *(const float4*)(xr + 484 + kg * 8) : z4;
        XMM(ta, tb, 15);
    }
#undef XMM

    #pragma unroll
    for (int t = 0; t < 4; ++t) {
        float bb = b1[t * 16 + r16];
        #pragma unroll
        for (int r = 0; r < 4; ++r) {
            float h = fmaxf(acc[t][r] + bb, 0.f);
            int row = kg * 4 + r;
            int col = (t * 16 + r16) ^ ((row & 7) << 3);
            hs[wid][row][col] = f2b(h);
        }
    }
    __syncthreads();

    f32x4 acc2[4];
    #pragma unroll
    for (int t = 0; t < 4; ++t) acc2[t] = (f32x4){0.f, 0.f, 0.f, 0.f};

    #pragma unroll
    for (int ks = 0; ks < 2; ++ks) {
        int colr = (ks * 32 + kg * 8) ^ ((r16 & 7) << 3);
        bf16x8 ha = *(const bf16x8*)&hs[wid][r16][colr];
        #pragma unroll
        for (int t = 0; t < 4; ++t) {
            bf16x8 wb = *(const bf16x8*)&w2t[(t * 16 + r16) * 64 + ks * 32 + kg * 8];
            acc2[t] = __builtin_amdgcn_mfma_f32_16x16x32_bf16(ha, wb, acc2[t], 0, 0, 0);
        }
    }

    #pragma unroll
    for (int t = 0; t < 4; ++t) {
        float bb = b2[t * 16 + r16];
        #pragma unroll
        for (int r = 0; r < 4; ++r) {
            int orow = rowbase + kg * 4 + r;
            if (orow < N_NODES) {
                float v = acc2[t][r] + bb;
                hb[orow * 64 + t * 16 + r16]  = f2b(v);
                ahb[orow * 64 + t * 16 + r16] = f2b(ALPHA * v);
            }
        }
    }
}

// ---------------------------------------------------------------------------
// CSR build: count -> scan -> 64-bucket split -> bucketed scatter -> row sort
// ---------------------------------------------------------------------------
__global__ __launch_bounds__(256) void zero_cnt(int* __restrict__ cnt)
{
    int i = blockIdx.x * 256 + threadIdx.x;
    if (i < N_NODES) cnt[i] = 0;
}

__global__ __launch_bounds__(256) void count_keys(
    const int* __restrict__ key, int* __restrict__ cnt)
{
    int i = blockIdx.x * 256 + threadIdx.x;
    if (i < N_EDGES) atomicAdd(&cnt[key[i]], 1);
}

__global__ __launch_bounds__(256) void scan_block_sums(
    const int* __restrict__ cnt, int* __restrict__ bsum)
{
    int i = blockIdx.x * 256 + threadIdx.x;
    int v = (i < N_NODES) ? cnt[i] : 0;
    for (int off = 32; off; off >>= 1) v += __shfl_down(v, off);
    __shared__ int ws_[4];
    if ((threadIdx.x & 63) == 0) ws_[threadIdx.x >> 6] = v;
    __syncthreads();
    if (threadIdx.x == 0) bsum[blockIdx.x] = ws_[0] + ws_[1] + ws_[2] + ws_[3];
}

__global__ __launch_bounds__(512) void scan_partials(
    const int* __restrict__ bsum, int* __restrict__ boff)
{
    int t = threadIdx.x;
    int v = (t < SCAN_B) ? bsum[t] : 0;
    int lane = t & 63, w = t >> 6;
    int x = v;
    for (int off = 1; off < 64; off <<= 1) {
        int y = __shfl_up(x, off);
        if (lane >= off) x += y;
    }
    __shared__ int wsum[8];
    if (lane == 63) wsum[w] = x;
    __syncthreads();
    if (w == 0) {
        int s = (lane < 8) ? wsum[lane] : 0;
        for (int off = 1; off < 8; off <<= 1) {
            int y = __shfl_up(s, off);
            if (lane >= off) s += y;
        }
        if (lane < 8) wsum[lane] = s;
    }
    __syncthreads();
    int wpre = (w == 0) ? 0 : wsum[w - 1];
    if (t < SCAN_B) boff[t] = wpre + x - v;
}

// seeds pcur[b] = row_start at each bucket's first dst (64 buckets)
__global__ __launch_bounds__(256) void scan_final(
    const int* __restrict__ cnt, const int* __restrict__ boff,
    int* __restrict__ row_start, int* __restrict__ pos,
    int* __restrict__ pcur)
{
    int i = blockIdx.x * 256 + threadIdx.x;
    int v = (i < N_NODES) ? cnt[i] : 0;
    int lane = threadIdx.x & 63, w = threadIdx.x >> 6;
    int x = v;
    for (int off = 1; off < 64; off <<= 1) {
        int y = __shfl_up(x, off);
        if (lane >= off) x += y;
    }
    __shared__ int wsum[4];
    if (lane == 63) wsum[w] = x;
    __syncthreads();
    int wpre = 0;
    for (int ww = 0; ww < w; ++ww) wpre += wsum[ww];
    int excl = wpre + x - v;
    int r = boff[blockIdx.x] + excl;
    if (i < N_NODES) {
        row_start[i] = r; pos[i] = r;
        int rel = i % PART_N;
        if (rel % SUB_N == 0) {                 // rel in {0,1563,...,10941}
            pcur[(i / PART_N) * 8 + rel / SUB_N] = r;
        }
    }
    if (i == 0) row_start[N_NODES] = N_EDGES;
}

// ---------------------------------------------------------------------------
// Pass A: 64-bucket split via LDS histogram (replaces 160-ballot sweep).
// Bucket b = (d/12500)*8 + (d%12500)/1563; each block histograms its 2560
// edges, reserves 64 contiguous runs with 64 global atomics, then writes
// edges compacted: sbuf becomes bucket-grouped with dense per-block runs
// (full-line writes). Entry: (rel<<17 | src, 0.9*w), rel = d % 12500 (14b).
// sbuf ALIASES ahb+hb — runs before mlp.
// ---------------------------------------------------------------------------
__global__ __launch_bounds__(256) void split_edges(
    const int* __restrict__ esrc, const int* __restrict__ edst,
    const float* __restrict__ ew, int* __restrict__ pcur,
    int2* __restrict__ sbuf)
{
    __shared__ int lhist[NBUCK];
    __shared__ int lbase[NBUCK];
    const int tid  = threadIdx.x;
    const int base = blockIdx.x * SPLIT_CHUNK;

    if (tid < NBUCK) lhist[tid] = 0;
    __syncthreads();

    int bk[SPLIT_ROUNDS];
    int dl[SPLIT_ROUNDS];
    #pragma unroll
    for (int k = 0; k < SPLIT_ROUNDS; ++k) {
        int d = edst[base + k * 256 + tid];
        int p = d / PART_N;
        int rel = d - p * PART_N;
        bk[k] = p * 8 + rel / SUB_N;
        dl[k] = rel;
        atomicAdd(&lhist[bk[k]], 1);
    }
    __syncthreads();
    if (tid < NBUCK) lbase[tid] = atomicAdd(&pcur[tid], lhist[tid]);
    __syncthreads();

    #pragma unroll
    for (int k = 0; k < SPLIT_ROUNDS; ++k) {
        int slot = atomicAdd(&lbase[bk[k]], 1);    // LDS
        int i = base + k * 256 + tid;
        sbuf[slot] = make_int2((dl[k] << 17) | esrc[i],
                               __float_as_int(0.9f * ew[i]));
    }
}

// ---------------------------------------------------------------------------
// Pass B: bucketed scatter. Block-group b (32 blocks) streams ONLY bucket
// b's contiguous sbuf range (NT loads, read once) and scatters into its
// ~400 KB csr window. Per XCD (blockIdx&7): 8 windows x 400 KB = 3.2 MB +
// transient stream < 4 MB L2 -> window lines survive until all ~8 entries
// arrive, one full writeback each. No cross-block timing assumptions.
// ---------------------------------------------------------------------------
__global__ __launch_bounds__(256) void fill_b(
    const int2* __restrict__ sbuf, const int* __restrict__ row_start,
    int* __restrict__ pos, int2* __restrict__ csr)
{
    const int b   = blockIdx.x & (NBUCK - 1);
    const int p   = b >> 3, sub = b & 7;
    const int dlo = p * PART_N + sub * SUB_N;
    int dhi = dlo + SUB_N;
    const int pend = p * PART_N + PART_N;
    if (dhi > pend) dhi = pend;
    const int lo_e = row_start[dlo];
    const int hi_e = row_start[dhi];          // b=63 -> row_start[N_NODES] ok
    const int stride = (FILL_GRID / NBUCK) * 256;   // 8192
    for (int i = lo_e + (blockIdx.x >> 6) * 256 + (int)threadIdx.x; i < hi_e;
         i += stride) {
        iv2 e = __builtin_nontemporal_load((const iv2*)sbuf + i);
        int d = p * PART_N + (((unsigned)e.x) >> 17);
        int q = atomicAdd(&pos[d], 1);
        csr[q] = make_int2(e.x & 0x1ffff, e.y);
    }
}

// In-row bitonic sort by src (locality only — correctness never depends on
// order). One wave per row; sorts first min(len,64) entries.
__global__ __launch_bounds__(256) void sort_rows(
    const int* __restrict__ row_start, int2* __restrict__ csr)
{
    const int node = blockIdx.x * 4 + (threadIdx.x >> 6);
    const int lane = threadIdx.x & 63;
    const int s0 = row_start[node];
    const int s1 = row_start[node + 1];
    int n = s1 - s0; if (n > 64) n = 64;
    int key = 0x7fffffff;
    int val = 0;
    if (lane < n) { int2 e = csr[s0 + lane]; key = e.x; val = e.y; }
    #pragma unroll
    for (int k = 2; k <= 64; k <<= 1) {
        #pragma unroll
        for (int j = k >> 1; j > 0; j >>= 1) {
            int pk = __shfl_xor(key, j, 64);
            int pv = __shfl_xor(val, j, 64);
            bool lower   = (lane & j) == 0;
            bool asc     = (lane & k) == 0;
            bool takeMin = (lower == asc);
            bool pick    = takeMin ? (pk < key) : (pk > key);
            if (pick) { key = pk; val = pv; }
        }
    }
    if (lane < n) csr[s0 + lane] = make_int2(key, val);
}

// ---------------------------------------------------------------------------
// Pull-based SpMM, bf16 z (round-5 version, known-good).
// ---------------------------------------------------------------------------
template <bool FINAL>
__global__ __launch_bounds__(256) void spmm_kernel(
    const int* __restrict__ row_start, const int2* __restrict__ csr,
    const ushort_t* __restrict__ zin, const ushort_t* __restrict__ ahb,
    void* __restrict__ zout)
{
    const int node = blockIdx.x * 4 + (threadIdx.x >> 6);  // 25000*4 == 100000
    const int lane = threadIdx.x & 63;
    const int g = lane >> 3;    // edge slot 0..7
    const int q = lane & 7;     // feature octet
    const int s0 = __builtin_amdgcn_readfirstlane(row_start[node]);
    const int s1 = __builtin_amdgcn_readfirstlane(row_start[node + 1]);

    float a0=0.f,a1=0.f,a2=0.f,a3=0.f,a4=0.f,a5=0.f,a6=0.f,a7=0.f;
    if (g == 0) {
        uint4 t = *(const uint4*)&ahb[node * 64 + 8 * q];
        a0 = bflo(t.x); a1 = bfhi(t.x); a2 = bflo(t.y); a3 = bfhi(t.y);
        a4 = bflo(t.z); a5 = bfhi(t.z); a6 = bflo(t.w); a7 = bfhi(t.w);
    }

#define FMA8(WV, ZV) do { \
        a0 = fmaf((WV), bflo((ZV).x), a0); a1 = fmaf((WV), bfhi((ZV).x), a1); \
        a2 = fmaf((WV), bflo((ZV).y), a2); a3 = fmaf((WV), bfhi((ZV).y), a3); \
        a4 = fmaf((WV), bflo((ZV).z), a4); a5 = fmaf((WV), bfhi((ZV).z), a5); \
        a6 = fmaf((WV), bflo((ZV).w), a6); a7 = fmaf((WV), bfhi((ZV).w), a7); \
    } while (0)

    int j = s0;
    for (; j + 32 <= s1; j += 32) {
        int2 e0 = csr[j + g];
        int2 e1 = csr[j + 8 + g];
        int2 e2 = csr[j + 16 + g];
        int2 e3 = csr[j + 24 + g];
        uint4 z0 = *(const uint4*)&zin[e0.x * 64 + 8 * q];
        uint4 z1 = *(const uint4*)&zin[e1.x * 64 + 8 * q];
        uint4 z2 = *(const uint4*)&zin[e2.x * 64 + 8 * q];
        uint4 z3 = *(const uint4*)&zin[e3.x * 64 + 8 * q];
        float w0 = __int_as_float(e0.y);
        float w1 = __int_as_float(e1.y);
        float w2 = __int_as_float(e2.y);
        float w3 = __int_as_float(e3.y);
        FMA8(w0, z0);
        FMA8(w1, z1);
        FMA8(w2, z2);
        FMA8(w3, z3);
    }
    for (; j < s1; j += 8) {
        int2 e = make_int2(0, 0);
        int jj = j + g;
        if (jj < s1) e = csr[jj];
        uint4 zt = *(const uint4*)&zin[e.x * 64 + 8 * q];
        float wt = __int_as_float(e.y);
        FMA8(wt, zt);
    }
#undef FMA8

    // reduce the 8 edge-slot groups (lane bits 3,4,5)
    #pragma unroll
    for (int m = 8; m <= 32; m <<= 1) {
        a0 += __shfl_xor(a0, m, 64); a1 += __shfl_xor(a1, m, 64);
        a2 += __shfl_xor(a2, m, 64); a3 += __shfl_xor(a3, m, 64);
        a4 += __shfl_xor(a4, m, 64); a5 += __shfl_xor(a5, m, 64);
        a6 += __shfl_xor(a6, m, 64); a7 += __shfl_xor(a7, m, 64);
    }

    if (g == 0) {
        if (FINAL) {
            float* op = (float*)zout + node * 64 + 8 * q;
            *(float4*)op       = make_float4(a0, a1, a2, a3);
            *(float4*)(op + 4) = make_float4(a4, a5, a6, a7);
        } else {
            uint4 pk;
            pk.x = packbf(a0, a1); pk.y = packbf(a2, a3);
            pk.z = packbf(a4, a5); pk.w = packbf(a6, a7);
            *(uint4*)&((ushort_t*)zout)[node * 64 + 8 * q] = pk;
        }
    }
}

// ---------------------------------------------------------------------------
extern "C" void kernel_launch(void* const* d_in, const int* in_sizes, int n_in,
                              void* d_out, int out_size, void* d_ws, size_t ws_size,
                              hipStream_t stream)
{
    const float* x    = (const float*)d_in[0];
    const int*   esrc = (const int*)d_in[1];
    const int*   edst = (const int*)d_in[2];
    const float* ew   = (const float*)d_in[3];
    const float* W1   = (const float*)d_in[4];
    const float* b1   = (const float*)d_in[5];
    const float* W2   = (const float*)d_in[6];
    const float* b2   = (const float*)d_in[7];
    float* out = (float*)d_out;

    // workspace layout (~65 MB). sbuf (25.6 MB) ALIASES ahb+hb: the CSR build
    // (split+fill_b) runs before mlp_mfma writes hb/ahb.
    char* p = (char*)d_ws;
    ushort_t* ahb = (ushort_t*)p;  p += (size_t)N_NODES * 64 * 2;   // 12.8M
    ushort_t* hb  = (ushort_t*)p;  p += (size_t)N_NODES * 64 * 2;   // 12.8M
    ushort_t* zB  = (ushort_t*)p;  p += (size_t)N_NODES * 64 * 2;   // 12.8M
    int2*  csr     = (int2*)p;     p += (size_t)N_EDGES * 8;        // 25.6M
    int* cnt       = (int*)p;      p += (size_t)N_NODES * 4;
    int* pos       = (int*)p;      p += (size_t)N_NODES * 4;
    int* row_start = (int*)p;      p += (size_t)(N_NODES + 1) * 4;
    int* bsum      = (int*)p;      p += (size_t)SCAN_B * 4;
    int* boff      = (int*)p;      p += (size_t)SCAN_B * 4;
    int* pcur      = (int*)p;      p += (size_t)NBUCK * 4;
    ushort_t* w1t  = (ushort_t*)p; p += (size_t)64 * KPAD * 2;      // 64 KB
    ushort_t* w2t  = (ushort_t*)p; p += (size_t)64 * 64 * 2;        // 8 KB
    int2* sbuf = (int2*)ahb;       // alias: 25.6 MB over ahb+hb

    const int EB = (N_EDGES + 255) / 256;

    hipLaunchKernelGGL(prep_weights, dim3((64 * KPAD + 64 * 64 + 255) / 256),
                       dim3(256), 0, stream, W1, W2, w1t, w2t);

    // CSR build first (sbuf aliases ahb/hb, so this precedes mlp)
    hipLaunchKernelGGL(zero_cnt, dim3(SCAN_B), dim3(256), 0, stream, cnt);
    hipLaunchKernelGGL(count_keys, dim3(EB), dim3(256), 0, stream, edst, cnt);
    hipLaunchKernelGGL(scan_block_sums, dim3(SCAN_B), dim3(256), 0, stream, cnt, bsum);
    hipLaunchKernelGGL(scan_partials, dim3(1), dim3(512), 0, stream, bsum, boff);
    hipLaunchKernelGGL(scan_final, dim3(SCAN_B), dim3(256), 0, stream,
                       cnt, boff, row_start, pos, pcur);
    hipLaunchKernelGGL(split_edges, dim3(SPLIT_GRID), dim3(256), 0, stream,
                       esrc, edst, ew, pcur, sbuf);
    hipLaunchKernelGGL(fill_b, dim3(FILL_GRID), dim3(256), 0, stream,
                       sbuf, row_start, pos, csr);
    hipLaunchKernelGGL(sort_rows, dim3(N_NODES / 4), dim3(256), 0, stream,
                       row_start, csr);

    // MLP after CSR build (frees the sbuf alias)
    hipLaunchKernelGGL(mlp_mfma, dim3((N_NODES + 63) / 64), dim3(256), 0, stream,
                       x, w1t, b1, w2t, b2, hb, ahb);

    // propagation: strict alternation. it even: ->zB, it odd: ->hb.
    // it=0: hb->zB; ... it=8: hb->zB; final (it=9): zB->out(fp32).
    const ushort_t* zi = hb;
    for (int it = 0; it < K_ITERS - 1; ++it) {
        ushort_t* zo = (it % 2 == 0) ? zB : hb;
        hipLaunchKernelGGL((spmm_kernel<false>), dim3(N_NODES / 4), dim3(256), 0, stream,
                           row_start, csr, zi, ahb, (void*)zo);
        zi = zo;
    }
    hipLaunchKernelGGL((spmm_kernel<true>), dim3(N_NODES / 4), dim3(256), 0, stream,
                       row_start, csr, zi, ahb, (void*)out);
}

// Round 10
// 1169.881 us; speedup vs baseline: 3.1985x; 1.0887x over previous
//
#include <hip/hip_runtime.h>

#define N_NODES 100000
#define N_EDGES 3200000
#define IN_F 500
#define HID 64
#define OUT_F 64
#define ALPHA 0.1f
#define K_ITERS 10
#define SCAN_B ((N_NODES + 255) / 256)   // 391

#define NPART 8                          // XCD count (m09)
#define PART_N (N_NODES / NPART)         // 12500
#define SUB_N 1563                       // 8 sub-buckets per partition
#define NBUCK 64                         // total dst buckets
#define FILL_GRID 2048                   // 64 buckets x 32 blocks

#define SPLIT_CHUNK 2560                 // edges per block in split_edges
#define SPLIT_ROUNDS 10                  // 2560 / 256
#define SPLIT_GRID (N_EDGES / SPLIT_CHUNK)   // 1250 exactly

#define BC_CHUNK 5120                    // edges per block in bucket_count
#define BC_ROUNDS 20
#define BC_GRID (N_EDGES / BC_CHUNK)     // 625 exactly

#define NC_PER 8                         // blocks per bucket in node_count

#define KPAD 512                // IN_F padded to MFMA K-step multiple

typedef unsigned short ushort_t;
typedef unsigned int uint_t;
typedef __attribute__((ext_vector_type(8))) short bf16x8;   // MFMA A/B frag
typedef __attribute__((ext_vector_type(4))) float f32x4;    // MFMA C/D frag
typedef int iv2 __attribute__((ext_vector_type(2)));        // NT-loadable int2

__device__ __forceinline__ float bf2f(ushort_t v) {
    union { uint_t u; float f; } c; c.u = ((uint_t)v) << 16; return c.f;
}
__device__ __forceinline__ ushort_t f2b(float f) {
    union { float f; uint_t u; } c; c.f = f;
    uint_t u = c.u + 0x7fffu + ((c.u >> 16) & 1u);   // round-to-nearest-even
    return (ushort_t)(u >> 16);
}
__device__ __forceinline__ float bflo(uint_t u) {
    union { uint_t u; float f; } c; c.u = u << 16; return c.f;
}
__device__ __forceinline__ float bfhi(uint_t u) {
    union { uint_t u; float f; } c; c.u = u & 0xffff0000u; return c.f;
}
__device__ __forceinline__ uint_t packbf(float a, float b) {
    return (uint_t)f2b(a) | ((uint_t)f2b(b) << 16);
}
__device__ __forceinline__ bf16x8 pack8(float4 a, float4 b) {
    bf16x8 r;
    r[0] = (short)f2b(a.x); r[1] = (short)f2b(a.y);
    r[2] = (short)f2b(a.z); r[3] = (short)f2b(a.w);
    r[4] = (short)f2b(b.x); r[5] = (short)f2b(b.y);
    r[6] = (short)f2b(b.z); r[7] = (short)f2b(b.w);
    return r;
}

// ---------------------------------------------------------------------------
// Weight prep: W1 -> w1t bf16 [64][512] (transposed, K zero-padded),
// W2 -> w2t bf16 [64][64] (transposed). One-shot.
// ---------------------------------------------------------------------------
__global__ __launch_bounds__(256) void prep_weights(
    const float* __restrict__ W1, const float* __restrict__ W2,
    ushort_t* __restrict__ w1t, ushort_t* __restrict__ w2t)
{
    int i = blockIdx.x * 256 + threadIdx.x;
    if (i < 64 * KPAD) {
        int c = i >> 9, k = i & (KPAD - 1);
        float v = (k < IN_F) ? W1[k * HID + c] : 0.f;
        w1t[c * KPAD + k] = f2b(v);
    } else {
        int j = i - 64 * KPAD;
        if (j < 64 * 64) {
            int c = j >> 6, k = j & 63;
            w2t[c * 64 + k] = f2b(W2[k * OUT_F + c]);
        }
    }
}

// ---------------------------------------------------------------------------
// MFMA MLP (round-8 version: LDS double-buffered x staging; left top-5).
// ---------------------------------------------------------------------------
__global__ __launch_bounds__(256, 2) void mlp_mfma(
    const float* __restrict__ x, const ushort_t* __restrict__ w1t,
    const float* __restrict__ b1, const ushort_t* __restrict__ w2t,
    const float* __restrict__ b2, ushort_t* __restrict__ hb,
    ushort_t* __restrict__ ahb)
{
    __shared__ float xs[2][64][32];      // 2 x 8 KB staging tiles
    __shared__ ushort_t hs[4][16][64];   // layer-2 re-fragment tile, 8 KB

    const int tid  = threadIdx.x;
    const int lane = tid & 63;
    const int wid  = tid >> 6;
    const int r16  = lane & 15;
    const int kg   = lane >> 4;
    const int block_row = blockIdx.x * 64;
    const int rowbase   = block_row + wid * 16;

    const int s_row0 = tid >> 3;               // 0..31
    const int s_row1 = s_row0 + 32;            // 32..63
    const int s_c    = tid & 7;
    int grow0 = block_row + s_row0; if (grow0 > N_NODES - 1) grow0 = N_NODES - 1;
    int grow1 = block_row + s_row1; if (grow1 > N_NODES - 1) grow1 = N_NODES - 1;
    const float* gx0 = x + (size_t)grow0 * IN_F + s_c * 4;
    const float* gx1 = x + (size_t)grow1 * IN_F + s_c * 4;
    char* xsb = (char*)&xs[0][0][0];
    const int ld0 = s_row0 * 128 + ((s_c ^ (s_row0 & 7)) * 16);
    const int ld1 = s_row1 * 128 + ((s_c ^ (s_row1 & 7)) * 16);

    f32x4 acc[4];
    #pragma unroll
    for (int t = 0; t < 4; ++t) acc[t] = (f32x4){0.f, 0.f, 0.f, 0.f};

    const int lrow  = wid * 16 + r16;
    const int swz   = lrow & 7;
    const int rbase = lrow * 128;
    const int off_a = rbase + (((kg * 2)     ^ swz) * 16);
    const int off_b = rbase + (((kg * 2 + 1) ^ swz) * 16);

#define XMM(PA, PB, KS) do {                                      \
        bf16x8 af_ = pack8(PA, PB);                               \
        _Pragma("unroll")                                         \
        for (int t = 0; t < 4; ++t) {                             \
            bf16x8 bw_ = *(const bf16x8*)&w1t[(t * 16 + r16) * KPAD + (KS) * 32 + kg * 8]; \
            acc[t] = __builtin_amdgcn_mfma_f32_16x16x32_bf16(af_, bw_, acc[t], 0, 0, 0);   \
        }                                                         \
    } while (0)

    float4 va = *(const float4*)(gx0);
    float4 vb = *(const float4*)(gx1);
    *(float4*)(xsb + ld0) = va;
    *(float4*)(xsb + ld1) = vb;
    __syncthreads();

    int cur = 0;
    for (int ks = 0; ks < 15; ++ks) {
        if (ks < 14) {
            va = *(const float4*)(gx0 + (ks + 1) * 32);
            vb = *(const float4*)(gx1 + (ks + 1) * 32);
        }
        const char* bb = xsb + cur * 8192;
        float4 fa = *(const float4*)(bb + off_a);
        float4 fb = *(const float4*)(bb + off_b);
        XMM(fa, fb, ks);
        __syncthreads();
        if (ks < 14) {
            char* wb = xsb + (cur ^ 1) * 8192;
            *(float4*)(wb + ld0) = va;
            *(float4*)(wb + ld1) = vb;
        }
        __syncthreads();
        cur ^= 1;
    }

    {
        const float4 z4 = make_float4(0.f, 0.f, 0.f, 0.f);
        int arow = rowbase + r16;
        int lrow2 = (arow < N_NODES) ? arow : (N_NODES - 1);
        const float* xr = x + (size_t)lrow2 * IN_F;
        float4 ta = (kg <= 2) ? *(const float4*)(xr + 480 + kg * 8) : z4;
        float4 tb = (kg <= 1) ? *(const float4*)(xr + 484 + kg * 8) : z4;
        XMM(ta, tb, 15);
    }
#undef XMM

    #pragma unroll
    for (int t = 0; t < 4; ++t) {
        float bb = b1[t * 16 + r16];
        #pragma unroll
        for (int r = 0; r < 4; ++r) {
            float h = fmaxf(acc[t][r] + bb, 0.f);
            int row = kg * 4 + r;
            int col = (t * 16 + r16) ^ ((row & 7) << 3);
            hs[wid][row][col] = f2b(h);
        }
    }
    __syncthreads();

    f32x4 acc2[4];
    #pragma unroll
    for (int t = 0; t < 4; ++t) acc2[t] = (f32x4){0.f, 0.f, 0.f, 0.f};

    #pragma unroll
    for (int ks = 0; ks < 2; ++ks) {
        int colr = (ks * 32 + kg * 8) ^ ((r16 & 7) << 3);
        bf16x8 ha = *(const bf16x8*)&hs[wid][r16][colr];
        #pragma unroll
        for (int t = 0; t < 4; ++t) {
            bf16x8 wb = *(const bf16x8*)&w2t[(t * 16 + r16) * 64 + ks * 32 + kg * 8];
            acc2[t] = __builtin_amdgcn_mfma_f32_16x16x32_bf16(ha, wb, acc2[t], 0, 0, 0);
        }
    }

    #pragma unroll
    for (int t = 0; t < 4; ++t) {
        float bb = b2[t * 16 + r16];
        #pragma unroll
        for (int r = 0; r < 4; ++r) {
            int orow = rowbase + kg * 4 + r;
            if (orow < N_NODES) {
                float v = acc2[t][r] + bb;
                hb[orow * 64 + t * 16 + r16]  = f2b(v);
                ahb[orow * 64 + t * 16 + r16] = f2b(ALPHA * v);
            }
        }
    }
}

// ---------------------------------------------------------------------------
// CSR build v3: bucket_count -> bucket_scan -> split -> node_count (LDS) ->
// node scans -> bucketed scatter -> row sort.
// Round-9 lesson: 3.2M global atomics in count_keys = ~100 MB write-through
// (32 B per atomic). Bucket counting uses 64 LDS slots + 64 global atomics
// per block; per-node counting runs on bucket-localized sbuf with <=1563-slot
// LDS histograms, merged with ~800K global adds (~25 MB).
// ---------------------------------------------------------------------------
__global__ __launch_bounds__(256) void zero_cnt(
    int* __restrict__ cnt, int* __restrict__ bcnt)
{
    int i = blockIdx.x * 256 + threadIdx.x;
    if (i < N_NODES) cnt[i] = 0;
    if (i < NBUCK) bcnt[i] = 0;
}

__global__ __launch_bounds__(256) void bucket_count(
    const int* __restrict__ edst, int* __restrict__ bcnt)
{
    __shared__ int lh[NBUCK];
    const int tid = threadIdx.x;
    if (tid < NBUCK) lh[tid] = 0;
    __syncthreads();
    const int base = blockIdx.x * BC_CHUNK;
    #pragma unroll 4
    for (int k = 0; k < BC_ROUNDS; ++k) {
        int d = edst[base + k * 256 + tid];
        int p = d / PART_N;
        int rel = d - p * PART_N;
        atomicAdd(&lh[p * 8 + rel / SUB_N], 1);
    }
    __syncthreads();
    if (tid < NBUCK && lh[tid]) atomicAdd(&bcnt[tid], lh[tid]);
}

// single wave: exclusive scan of 64 bucket totals -> bbase[65], seed bpcur
__global__ __launch_bounds__(64) void bucket_scan(
    const int* __restrict__ bcnt, int* __restrict__ bbase,
    int* __restrict__ bpcur)
{
    int lane = threadIdx.x;
    int v = bcnt[lane];
    int x = v;
    for (int off = 1; off < 64; off <<= 1) {
        int y = __shfl_up(x, off);
        if (lane >= off) x += y;
    }
    int excl = x - v;
    bbase[lane] = excl;
    bpcur[lane] = excl;
    if (lane == 63) bbase[64] = x;   // == N_EDGES
}

__global__ __launch_bounds__(256) void scan_block_sums(
    const int* __restrict__ cnt, int* __restrict__ bsum)
{
    int i = blockIdx.x * 256 + threadIdx.x;
    int v = (i < N_NODES) ? cnt[i] : 0;
    for (int off = 32; off; off >>= 1) v += __shfl_down(v, off);
    __shared__ int ws_[4];
    if ((threadIdx.x & 63) == 0) ws_[threadIdx.x >> 6] = v;
    __syncthreads();
    if (threadIdx.x == 0) bsum[blockIdx.x] = ws_[0] + ws_[1] + ws_[2] + ws_[3];
}

__global__ __launch_bounds__(512) void scan_partials(
    const int* __restrict__ bsum, int* __restrict__ boff)
{
    int t = threadIdx.x;
    int v = (t < SCAN_B) ? bsum[t] : 0;
    int lane = t & 63, w = t >> 6;
    int x = v;
    for (int off = 1; off < 64; off <<= 1) {
        int y = __shfl_up(x, off);
        if (lane >= off) x += y;
    }
    __shared__ int wsum[8];
    if (lane == 63) wsum[w] = x;
    __syncthreads();
    if (w == 0) {
        int s = (lane < 8) ? wsum[lane] : 0;
        for (int off = 1; off < 8; off <<= 1) {
            int y = __shfl_up(s, off);
            if (lane >= off) s += y;
        }
        if (lane < 8) wsum[lane] = s;
    }
    __syncthreads();
    int wpre = (w == 0) ? 0 : wsum[w - 1];
    if (t < SCAN_B) boff[t] = wpre + x - v;
}

__global__ __launch_bounds__(256) void scan_final(
    const int* __restrict__ cnt, const int* __restrict__ boff,
    int* __restrict__ row_start, int* __restrict__ pos)
{
    int i = blockIdx.x * 256 + threadIdx.x;
    int v = (i < N_NODES) ? cnt[i] : 0;
    int lane = threadIdx.x & 63, w = threadIdx.x >> 6;
    int x = v;
    for (int off = 1; off < 64; off <<= 1) {
        int y = __shfl_up(x, off);
        if (lane >= off) x += y;
    }
    __shared__ int wsum[4];
    if (lane == 63) wsum[w] = x;
    __syncthreads();
    int wpre = 0;
    for (int ww = 0; ww < w; ++ww) wpre += wsum[ww];
    int excl = wpre + x - v;
    int r = boff[blockIdx.x] + excl;
    if (i < N_NODES) { row_start[i] = r; pos[i] = r; }
    if (i == 0) row_start[N_NODES] = N_EDGES;
}

// ---------------------------------------------------------------------------
// 64-bucket split via LDS histogram. Bucket b = (d/12500)*8 + (d%12500)/1563;
// block reserves 64 contiguous runs with 64 global atomics on bpcur (seeded
// from bucket_scan), then writes edges compacted (full-line runs).
// Entry: (rel<<17 | src, 0.9*w), rel = d % 12500. sbuf ALIASES ahb+hb.
// ---------------------------------------------------------------------------
__global__ __launch_bounds__(256) void split_edges(
    const int* __restrict__ esrc, const int* __restrict__ edst,
    const float* __restrict__ ew, int* __restrict__ bpcur,
    int2* __restrict__ sbuf)
{
    __shared__ int lhist[NBUCK];
    __shared__ int lbase[NBUCK];
    const int tid  = threadIdx.x;
    const int base = blockIdx.x * SPLIT_CHUNK;

    if (tid < NBUCK) lhist[tid] = 0;
    __syncthreads();

    int bk[SPLIT_ROUNDS];
    int dl[SPLIT_ROUNDS];
    #pragma unroll
    for (int k = 0; k < SPLIT_ROUNDS; ++k) {
        int d = edst[base + k * 256 + tid];
        int p = d / PART_N;
        int rel = d - p * PART_N;
        bk[k] = p * 8 + rel / SUB_N;
        dl[k] = rel;
        atomicAdd(&lhist[bk[k]], 1);
    }
    __syncthreads();
    if (tid < NBUCK) lbase[tid] = atomicAdd(&bpcur[tid], lhist[tid]);
    __syncthreads();

    #pragma unroll
    for (int k = 0; k < SPLIT_ROUNDS; ++k) {
        int slot = atomicAdd(&lbase[bk[k]], 1);    // LDS
        int i = base + k * 256 + tid;
        sbuf[slot] = make_int2((dl[k] << 17) | esrc[i],
                               __float_as_int(0.9f * ew[i]));
    }
}

// ---------------------------------------------------------------------------
// Per-node counts from bucket-localized sbuf. NC_PER blocks per bucket each
// stream a strided slice (NT), LDS-histogram the bucket's <=1563 nodes, then
// merge nonzero slots with one global atomicAdd each (~800K total).
// ---------------------------------------------------------------------------
__global__ __launch_bounds__(256) void node_count(
    const int2* __restrict__ sbuf, const int* __restrict__ bbase,
    int* __restrict__ cnt)
{
    __shared__ int lh[SUB_N];
    const int tid = threadIdx.x;
    const int b   = blockIdx.x & (NBUCK - 1);
    const int j   = blockIdx.x >> 6;             // 0..NC_PER-1
    const int p   = b >> 3, sub = b & 7;
    const int rel0 = sub * SUB_N;

    for (int s = tid; s < SUB_N; s += 256) lh[s] = 0;
    __syncthreads();

    const int lo = bbase[b];
    const int hi = bbase[b + 1];
    for (int i = lo + j * 256 + tid; i < hi; i += NC_PER * 256) {
        iv2 e = __builtin_nontemporal_load((const iv2*)sbuf + i);
        int rel = ((unsigned)e.x) >> 17;
        atomicAdd(&lh[rel - rel0], 1);
    }
    __syncthreads();

    for (int s = tid; s < SUB_N; s += 256) {
        int c = lh[s];
        if (c) atomicAdd(&cnt[p * PART_N + rel0 + s], c);
    }
}

// ---------------------------------------------------------------------------
// Bucketed scatter (round-9 version; ranges now from bbase). Block-group b
// (32 blocks) streams bucket b's sbuf range (NT) and scatters into its
// ~400 KB csr window; per XCD 8 windows = 3.2 MB < 4 MB L2.
// ---------------------------------------------------------------------------
__global__ __launch_bounds__(256) void fill_b(
    const int2* __restrict__ sbuf, const int* __restrict__ bbase,
    int* __restrict__ pos, int2* __restrict__ csr)
{
    const int b   = blockIdx.x & (NBUCK - 1);
    const int p   = b >> 3;
    const int lo_e = bbase[b];
    const int hi_e = bbase[b + 1];
    const int stride = (FILL_GRID / NBUCK) * 256;   // 8192
    for (int i = lo_e + (blockIdx.x >> 6) * 256 + (int)threadIdx.x; i < hi_e;
         i += stride) {
        iv2 e = __builtin_nontemporal_load((const iv2*)sbuf + i);
        int d = p * PART_N + (((unsigned)e.x) >> 17);
        int q = atomicAdd(&pos[d], 1);
        csr[q] = make_int2(e.x & 0x1ffff, e.y);
    }
}

// In-row bitonic sort by src (locality only). One wave per row.
__global__ __launch_bounds__(256) void sort_rows(
    const int* __restrict__ row_start, int2* __restrict__ csr)
{
    const int node = blockIdx.x * 4 + (threadIdx.x >> 6);
    const int lane = threadIdx.x & 63;
    const int s0 = row_start[node];
    const int s1 = row_start[node + 1];
    int n = s1 - s0; if (n > 64) n = 64;
    int key = 0x7fffffff;
    int val = 0;
    if (lane < n) { int2 e = csr[s0 + lane]; key = e.x; val = e.y; }
    #pragma unroll
    for (int k = 2; k <= 64; k <<= 1) {
        #pragma unroll
        for (int j = k >> 1; j > 0; j >>= 1) {
            int pk = __shfl_xor(key, j, 64);
            int pv = __shfl_xor(val, j, 64);
            bool lower   = (lane & j) == 0;
            bool asc     = (lane & k) == 0;
            bool takeMin = (lower == asc);
            bool pick    = takeMin ? (pk < key) : (pk > key);
            if (pick) { key = pk; val = pv; }
        }
    }
    if (lane < n) csr[s0 + lane] = make_int2(key, val);
}

// ---------------------------------------------------------------------------
// Pull-based SpMM, bf16 z (round-5 version, known-good).
// ---------------------------------------------------------------------------
template <bool FINAL>
__global__ __launch_bounds__(256) void spmm_kernel(
    const int* __restrict__ row_start, const int2* __restrict__ csr,
    const ushort_t* __restrict__ zin, const ushort_t* __restrict__ ahb,
    void* __restrict__ zout)
{
    const int node = blockIdx.x * 4 + (threadIdx.x >> 6);  // 25000*4 == 100000
    const int lane = threadIdx.x & 63;
    const int g = lane >> 3;    // edge slot 0..7
    const int q = lane & 7;     // feature octet
    const int s0 = __builtin_amdgcn_readfirstlane(row_start[node]);
    const int s1 = __builtin_amdgcn_readfirstlane(row_start[node + 1]);

    float a0=0.f,a1=0.f,a2=0.f,a3=0.f,a4=0.f,a5=0.f,a6=0.f,a7=0.f;
    if (g == 0) {
        uint4 t = *(const uint4*)&ahb[node * 64 + 8 * q];
        a0 = bflo(t.x); a1 = bfhi(t.x); a2 = bflo(t.y); a3 = bfhi(t.y);
        a4 = bflo(t.z); a5 = bfhi(t.z); a6 = bflo(t.w); a7 = bfhi(t.w);
    }

#define FMA8(WV, ZV) do { \
        a0 = fmaf((WV), bflo((ZV).x), a0); a1 = fmaf((WV), bfhi((ZV).x), a1); \
        a2 = fmaf((WV), bflo((ZV).y), a2); a3 = fmaf((WV), bfhi((ZV).y), a3); \
        a4 = fmaf((WV), bflo((ZV).z), a4); a5 = fmaf((WV), bfhi((ZV).z), a5); \
        a6 = fmaf((WV), bflo((ZV).w), a6); a7 = fmaf((WV), bfhi((ZV).w), a7); \
    } while (0)

    int j = s0;
    for (; j + 32 <= s1; j += 32) {
        int2 e0 = csr[j + g];
        int2 e1 = csr[j + 8 + g];
        int2 e2 = csr[j + 16 + g];
        int2 e3 = csr[j + 24 + g];
        uint4 z0 = *(const uint4*)&zin[e0.x * 64 + 8 * q];
        uint4 z1 = *(const uint4*)&zin[e1.x * 64 + 8 * q];
        uint4 z2 = *(const uint4*)&zin[e2.x * 64 + 8 * q];
        uint4 z3 = *(const uint4*)&zin[e3.x * 64 + 8 * q];
        float w0 = __int_as_float(e0.y);
        float w1 = __int_as_float(e1.y);
        float w2 = __int_as_float(e2.y);
        float w3 = __int_as_float(e3.y);
        FMA8(w0, z0);
        FMA8(w1, z1);
        FMA8(w2, z2);
        FMA8(w3, z3);
    }
    for (; j < s1; j += 8) {
        int2 e = make_int2(0, 0);
        int jj = j + g;
        if (jj < s1) e = csr[jj];
        uint4 zt = *(const uint4*)&zin[e.x * 64 + 8 * q];
        float wt = __int_as_float(e.y);
        FMA8(wt, zt);
    }
#undef FMA8

    // reduce the 8 edge-slot groups (lane bits 3,4,5)
    #pragma unroll
    for (int m = 8; m <= 32; m <<= 1) {
        a0 += __shfl_xor(a0, m, 64); a1 += __shfl_xor(a1, m, 64);
        a2 += __shfl_xor(a2, m, 64); a3 += __shfl_xor(a3, m, 64);
        a4 += __shfl_xor(a4, m, 64); a5 += __shfl_xor(a5, m, 64);
        a6 += __shfl_xor(a6, m, 64); a7 += __shfl_xor(a7, m, 64);
    }

    if (g == 0) {
        if (FINAL) {
            float* op = (float*)zout + node * 64 + 8 * q;
            *(float4*)op       = make_float4(a0, a1, a2, a3);
            *(float4*)(op + 4) = make_float4(a4, a5, a6, a7);
        } else {
            uint4 pk;
            pk.x = packbf(a0, a1); pk.y = packbf(a2, a3);
            pk.z = packbf(a4, a5); pk.w = packbf(a6, a7);
            *(uint4*)&((ushort_t*)zout)[node * 64 + 8 * q] = pk;
        }
    }
}

// ---------------------------------------------------------------------------
extern "C" void kernel_launch(void* const* d_in, const int* in_sizes, int n_in,
                              void* d_out, int out_size, void* d_ws, size_t ws_size,
                              hipStream_t stream)
{
    const float* x    = (const float*)d_in[0];
    const int*   esrc = (const int*)d_in[1];
    const int*   edst = (const int*)d_in[2];
    const float* ew   = (const float*)d_in[3];
    const float* W1   = (const float*)d_in[4];
    const float* b1   = (const float*)d_in[5];
    const float* W2   = (const float*)d_in[6];
    const float* b2   = (const float*)d_in[7];
    float* out = (float*)d_out;

    // workspace layout (~65 MB). sbuf (25.6 MB) ALIASES ahb+hb: the CSR build
    // runs before mlp_mfma writes hb/ahb.
    char* p = (char*)d_ws;
    ushort_t* ahb = (ushort_t*)p;  p += (size_t)N_NODES * 64 * 2;   // 12.8M
    ushort_t* hb  = (ushort_t*)p;  p += (size_t)N_NODES * 64 * 2;   // 12.8M
    ushort_t* zB  = (ushort_t*)p;  p += (size_t)N_NODES * 64 * 2;   // 12.8M
    int2*  csr     = (int2*)p;     p += (size_t)N_EDGES * 8;        // 25.6M
    int* cnt       = (int*)p;      p += (size_t)N_NODES * 4;
    int* pos       = (int*)p;      p += (size_t)N_NODES * 4;
    int* row_start = (int*)p;      p += (size_t)(N_NODES + 1) * 4;
    int* bsum      = (int*)p;      p += (size_t)SCAN_B * 4;
    int* boff      = (int*)p;      p += (size_t)SCAN_B * 4;
    int* bcnt      = (int*)p;      p += (size_t)NBUCK * 4;
    int* bbase     = (int*)p;      p += (size_t)(NBUCK + 1) * 4;
    int* bpcur     = (int*)p;      p += (size_t)NBUCK * 4;
    ushort_t* w1t  = (ushort_t*)p; p += (size_t)64 * KPAD * 2;      // 64 KB
    ushort_t* w2t  = (ushort_t*)p; p += (size_t)64 * 64 * 2;        // 8 KB
    int2* sbuf = (int2*)ahb;       // alias: 25.6 MB over ahb+hb

    hipLaunchKernelGGL(prep_weights, dim3((64 * KPAD + 64 * 64 + 255) / 256),
                       dim3(256), 0, stream, W1, W2, w1t, w2t);

    // CSR build (sbuf aliases ahb/hb, so this precedes mlp)
    hipLaunchKernelGGL(zero_cnt, dim3(SCAN_B), dim3(256), 0, stream, cnt, bcnt);
    hipLaunchKernelGGL(bucket_count, dim3(BC_GRID), dim3(256), 0, stream,
                       edst, bcnt);
    hipLaunchKernelGGL(bucket_scan, dim3(1), dim3(64), 0, stream,
                       bcnt, bbase, bpcur);
    hipLaunchKernelGGL(split_edges, dim3(SPLIT_GRID), dim3(256), 0, stream,
                       esrc, edst, ew, bpcur, sbuf);
    hipLaunchKernelGGL(node_count, dim3(NBUCK * NC_PER), dim3(256), 0, stream,
                       sbuf, bbase, cnt);
    hipLaunchKernelGGL(scan_block_sums, dim3(SCAN_B), dim3(256), 0, stream, cnt, bsum);
    hipLaunchKernelGGL(scan_partials, dim3(1), dim3(512), 0, stream, bsum, boff);
    hipLaunchKernelGGL(scan_final, dim3(SCAN_B), dim3(256), 0, stream,
                       cnt, boff, row_start, pos);
    hipLaunchKernelGGL(fill_b, dim3(FILL_GRID), dim3(256), 0, stream,
                       sbuf, bbase, pos, csr);
    hipLaunchKernelGGL(sort_rows, dim3(N_NODES / 4), dim3(256), 0, stream,
                       row_start, csr);

    // MLP after CSR build (frees the sbuf alias)
    hipLaunchKernelGGL(mlp_mfma, dim3((N_NODES + 63) / 64), dim3(256), 0, stream,
                       x, w1t, b1, w2t, b2, hb, ahb);

    // propagation: strict alternation. it even: ->zB, it odd: ->hb.
    // it=0: hb->zB; ... it=8: hb->zB; final (it=9): zB->out(fp32).
    const ushort_t* zi = hb;
    for (int it = 0; it < K_ITERS - 1; ++it) {
        ushort_t* zo = (it % 2 == 0) ? zB : hb;
        hipLaunchKernelGGL((spmm_kernel<false>), dim3(N_NODES / 4), dim3(256), 0, stream,
                           row_start, csr, zi, ahb, (void*)zo);
        zi = zo;
    }
    hipLaunchKernelGGL((spmm_kernel<true>), dim3(N_NODES / 4), dim3(256), 0, stream,
                       row_start, csr, zi, ahb, (void*)out);
}